// Round 1
// baseline (810.938 us; speedup 1.0000x reference)
//
#include <hip/hip_runtime.h>

#define N_NODES 100000
#define NH 64

// ---------------- graph preprocessing ----------------

__global__ __launch_bounds__(256) void k_zero(int* __restrict__ cnt, int n) {
    int i = blockIdx.x * 256 + threadIdx.x;
    if (i < n) cnt[i] = 0;
}

__global__ __launch_bounds__(256) void k_hist(const int* __restrict__ dst, int* __restrict__ cnt, int e) {
    int i = blockIdx.x * 256 + threadIdx.x;
    if (i < e) atomicAdd(&cnt[dst[i]], 1);
}

// single-block exclusive scan over n counts -> rowptr[0..n]
__global__ __launch_bounds__(1024) void k_scan(const int* __restrict__ cnt, int* __restrict__ rowptr, int n) {
    __shared__ int sums[1024];
    int t = threadIdx.x;
    int chunk = (n + 1023) >> 10;
    int lo = t * chunk; if (lo > n) lo = n;
    int hi = lo + chunk; if (hi > n) hi = n;
    int s = 0;
    for (int i = lo; i < hi; ++i) { rowptr[i] = s; s += cnt[i]; }
    sums[t] = s;
    __syncthreads();
    if (t == 0) {
        int run = 0;
        for (int k = 0; k < 1024; ++k) { int v = sums[k]; sums[k] = run; run += v; }
        rowptr[n] = run;
    }
    __syncthreads();
    int off = sums[t];
    for (int i = lo; i < hi; ++i) rowptr[i] += off;
}

__global__ __launch_bounds__(256) void k_prep(const int* __restrict__ cnt, const int* __restrict__ rowptr,
                                              float* __restrict__ dinv, int* __restrict__ cursor, int n) {
    int i = blockIdx.x * 256 + threadIdx.x;
    if (i < n) {
        dinv[i] = rsqrtf((float)(cnt[i] + 1));  // +1 self loop
        cursor[i] = rowptr[i];
    }
}

__global__ __launch_bounds__(256) void k_fill(const int* __restrict__ src, const int* __restrict__ dst,
                                              int* __restrict__ cursor, int* __restrict__ csrc, int e) {
    int i = blockIdx.x * 256 + threadIdx.x;
    if (i < e) {
        int d = dst[i];
        int pos = atomicAdd(&cursor[d], 1);
        csrc[pos] = src[i];
    }
}

// ---------------- GEMM: out[node][c] = (sum_k X[node][k]*W[k][c]) * dinv[node] ----------------
// block = 256 threads, tile = 64 nodes x 64 cols, thread tile 4x4.

template <int K>
__global__ __launch_bounds__(256) void k_gemm_scale(const float* __restrict__ X, const float* __restrict__ W,
                                                    const float* __restrict__ dinv, float* __restrict__ out, int n) {
    __shared__ float xs[64][132];      // +4 pad: bank = (4*row + k) % 32
    __shared__ float ws[K][64];
    const int tid = threadIdx.x;
    const int n0 = blockIdx.x * 64;

    // load W (K*64 floats)
    float* wsf = &ws[0][0];
    for (int idx = tid * 4; idx < K * 64; idx += 1024) {
        *(float4*)&wsf[idx] = *(const float4*)&W[idx];
    }
    // load X tile (contiguous chunk of 64 rows)
    const long long base = (long long)n0 * K;
    const long long lim = (long long)n * K;
    for (int idx = tid * 4; idx < 64 * K; idx += 1024) {
        float4 v = make_float4(0.f, 0.f, 0.f, 0.f);
        long long g = base + idx;
        if (g + 3 < lim) v = *(const float4*)&X[g];
        int row = idx / K, col = idx % K;
        *(float4*)&xs[row][col] = v;
    }
    __syncthreads();

    const int tc = tid & 15;    // col group: cols 4*tc..4*tc+3
    const int tn = tid >> 4;    // node group: rows 4*tn..4*tn+3
    float acc[4][4];
#pragma unroll
    for (int r = 0; r < 4; ++r)
#pragma unroll
        for (int c = 0; c < 4; ++c) acc[r][c] = 0.f;

#pragma unroll 4
    for (int k = 0; k < K; ++k) {
        float4 w = *(const float4*)&ws[k][tc * 4];
        float x0 = xs[4 * tn + 0][k];
        float x1 = xs[4 * tn + 1][k];
        float x2 = xs[4 * tn + 2][k];
        float x3 = xs[4 * tn + 3][k];
        acc[0][0] += x0 * w.x; acc[0][1] += x0 * w.y; acc[0][2] += x0 * w.z; acc[0][3] += x0 * w.w;
        acc[1][0] += x1 * w.x; acc[1][1] += x1 * w.y; acc[1][2] += x1 * w.z; acc[1][3] += x1 * w.w;
        acc[2][0] += x2 * w.x; acc[2][1] += x2 * w.y; acc[2][2] += x2 * w.z; acc[2][3] += x2 * w.w;
        acc[3][0] += x3 * w.x; acc[3][1] += x3 * w.y; acc[3][2] += x3 * w.z; acc[3][3] += x3 * w.w;
    }

#pragma unroll
    for (int r = 0; r < 4; ++r) {
        int node = n0 + 4 * tn + r;
        if (node < n) {
            float dv = dinv[node];
            float4 o;
            o.x = acc[r][0] * dv; o.y = acc[r][1] * dv; o.z = acc[r][2] * dv; o.w = acc[r][3] * dv;
            *(float4*)&out[(long long)node * NH + tc * 4] = o;
        }
    }
}

// ---------------- aggregation: one wave per node, lane = feature ----------------
// out[i] = relu(dinv[i] * (hs[i] + sum_{e:dst=i} hs[src_e]) + b) [+ resid[i]]

__global__ __launch_bounds__(256) void k_agg(const float* __restrict__ hs, const float* __restrict__ dinv,
                                             const int* __restrict__ rowptr, const int* __restrict__ csrc,
                                             const float* __restrict__ bias, const float* __restrict__ resid,
                                             float* __restrict__ out, int n) {
    int node = (int)((blockIdx.x * 256 + threadIdx.x) >> 6);
    int lane = threadIdx.x & 63;
    if (node >= n) return;
    long long rowbase = (long long)node * NH;
    float acc = hs[rowbase + lane];  // self loop
    int e0 = rowptr[node], e1 = rowptr[node + 1];
    for (int e = e0; e < e1; ++e) {
        int s = csrc[e];
        acc += hs[(long long)s * NH + lane];
    }
    float v = dinv[node] * acc + bias[lane];
    v = fmaxf(v, 0.f);
    if (resid) v += resid[rowbase + lane];
    out[rowbase + lane] = v;
}

// ---------------- launch ----------------

extern "C" void kernel_launch(void* const* d_in, const int* in_sizes, int n_in,
                              void* d_out, int out_size, void* d_ws, size_t ws_size,
                              hipStream_t stream) {
    const float* x  = (const float*)d_in[0];
    const int*   ei = (const int*)d_in[1];
    const float* W1 = (const float*)d_in[2];
    const float* b1 = (const float*)d_in[3];
    const float* W2 = (const float*)d_in[4];
    const float* b2 = (const float*)d_in[5];
    float* out = (float*)d_out;

    const int N = N_NODES;
    const int E = in_sizes[1] / 2;
    const int* src = ei;
    const int* dst = ei + E;

    // workspace layout (element offsets, all 16B-aligned)
    const int NP = 100352;  // padded N
    int*   cnt    = (int*)d_ws;
    int*   rowptr = cnt + NP;
    int*   cursor = rowptr + NP;
    float* dinv   = (float*)(cursor + NP);
    int*   csrc   = (int*)(dinv + NP);
    float* hs     = (float*)(csrc + 1600000);
    float* h1     = hs + (long long)N * NH;   // 6.4M floats each

    const int nb_n = (N + 255) / 256;
    const int nb_e = (E + 255) / 256;

    k_zero<<<nb_n, 256, 0, stream>>>(cnt, N);
    k_hist<<<nb_e, 256, 0, stream>>>(dst, cnt, E);
    k_scan<<<1, 1024, 0, stream>>>(cnt, rowptr, N);
    k_prep<<<nb_n, 256, 0, stream>>>(cnt, rowptr, dinv, cursor, N);
    k_fill<<<nb_e, 256, 0, stream>>>(src, dst, cursor, csrc, E);

    // layer 1
    k_gemm_scale<128><<<(N + 63) / 64, 256, 0, stream>>>(x, W1, dinv, hs, N);
    k_agg<<<(N + 3) / 4, 256, 0, stream>>>(hs, dinv, rowptr, csrc, b1, nullptr, h1, N);

    // layer 2 (+ residual h1)
    k_gemm_scale<64><<<(N + 63) / 64, 256, 0, stream>>>(h1, W2, dinv, hs, N);
    k_agg<<<(N + 3) / 4, 256, 0, stream>>>(hs, dinv, rowptr, csrc, b2, h1, out, N);
}

// Round 2
// 547.410 us; speedup vs baseline: 1.4814x; 1.4814x over previous
//
#include <hip/hip_runtime.h>

#define N_NODES 100000
#define NH 64

// ---------------- graph preprocessing ----------------

__global__ __launch_bounds__(256) void k_zero(int* __restrict__ cnt, int n) {
    int i = blockIdx.x * 256 + threadIdx.x;
    if (i < n) cnt[i] = 0;
}

__global__ __launch_bounds__(256) void k_hist(const int* __restrict__ dst, int* __restrict__ cnt, int e) {
    int i = blockIdx.x * 256 + threadIdx.x;
    if (i < e) atomicAdd(&cnt[dst[i]], 1);
}

// hierarchical scan, level 1: each block scans 1024 counts (4/thread),
// writes local exclusive scan to rowptr and its block total to bsum.
__global__ __launch_bounds__(256) void k_scan_local(const int* __restrict__ cnt, int* __restrict__ rowptr,
                                                    int* __restrict__ bsum, int n) {
    __shared__ int wsum[4];
    const int t = threadIdx.x;
    const int lane = t & 63, wave = t >> 6;
    const int base = blockIdx.x * 1024 + t * 4;
    int v0 = 0, v1 = 0, v2 = 0, v3 = 0;
    if (base + 3 < n) {
        int4 c = *(const int4*)&cnt[base];
        v0 = c.x; v1 = c.y; v2 = c.z; v3 = c.w;
    } else {
        if (base + 0 < n) v0 = cnt[base + 0];
        if (base + 1 < n) v1 = cnt[base + 1];
        if (base + 2 < n) v2 = cnt[base + 2];
    }
    const int s = v0 + v1 + v2 + v3;
    int inc = s;
#pragma unroll
    for (int d = 1; d < 64; d <<= 1) {
        int u = __shfl_up(inc, d, 64);
        if (lane >= d) inc += u;
    }
    if (lane == 63) wsum[wave] = inc;
    __syncthreads();
    int woff = 0;
#pragma unroll
    for (int w = 0; w < 4; ++w)
        if (w < wave) woff += wsum[w];
    int excl = woff + inc - s;
    if (base + 0 < n) rowptr[base + 0] = excl; excl += v0;
    if (base + 1 < n) rowptr[base + 1] = excl; excl += v1;
    if (base + 2 < n) rowptr[base + 2] = excl; excl += v2;
    if (base + 3 < n) rowptr[base + 3] = excl;
    if (t == 255) bsum[blockIdx.x] = woff + inc;
}

// level 2: one block scans the (<=256) block sums in place (exclusive),
// writes grand total to bsum[nb].
__global__ __launch_bounds__(256) void k_scan_bsum(int* __restrict__ bsum, int nb) {
    __shared__ int wsum[4];
    const int t = threadIdx.x;
    const int lane = t & 63, wave = t >> 6;
    const int v = (t < nb) ? bsum[t] : 0;
    int inc = v;
#pragma unroll
    for (int d = 1; d < 64; d <<= 1) {
        int u = __shfl_up(inc, d, 64);
        if (lane >= d) inc += u;
    }
    if (lane == 63) wsum[wave] = inc;
    __syncthreads();
    int woff = 0;
#pragma unroll
    for (int w = 0; w < 4; ++w)
        if (w < wave) woff += wsum[w];
    if (t < nb) bsum[t] = woff + inc - v;
    if (t == 255) bsum[nb] = woff + inc;
}

// level 3 fused with prep: apply block offsets, init cursor, compute dinv.
__global__ __launch_bounds__(256) void k_prep(const int* __restrict__ cnt, int* __restrict__ rowptr,
                                              const int* __restrict__ bsum, float* __restrict__ dinv,
                                              int* __restrict__ cursor, int n, int nb) {
    int i = blockIdx.x * 256 + threadIdx.x;
    if (i < n) {
        int rp = rowptr[i] + bsum[i >> 10];
        rowptr[i] = rp;
        cursor[i] = rp;
        dinv[i] = rsqrtf((float)(cnt[i] + 1));  // +1 self loop
    }
    if (i == n) rowptr[n] = bsum[nb];
}

__global__ __launch_bounds__(256) void k_fill(const int* __restrict__ src, const int* __restrict__ dst,
                                              int* __restrict__ cursor, int* __restrict__ csrc, int e) {
    int i = blockIdx.x * 256 + threadIdx.x;
    if (i < e) {
        int d = dst[i];
        int pos = atomicAdd(&cursor[d], 1);
        csrc[pos] = src[i];
    }
}

// ---------------- GEMM: out[node][c] = (sum_k X[node][k]*W[k][c]) * dinv[node] ----------------
// block = 256 threads, tile = 64 nodes x 64 cols, thread tile 4x4.

template <int K>
__global__ __launch_bounds__(256) void k_gemm_scale(const float* __restrict__ X, const float* __restrict__ W,
                                                    const float* __restrict__ dinv, float* __restrict__ out, int n) {
    __shared__ float xs[64][132];      // +4 pad: bank = (4*row + k) % 32
    __shared__ float ws[K][64];
    const int tid = threadIdx.x;
    const int n0 = blockIdx.x * 64;

    float* wsf = &ws[0][0];
    for (int idx = tid * 4; idx < K * 64; idx += 1024) {
        *(float4*)&wsf[idx] = *(const float4*)&W[idx];
    }
    const long long base = (long long)n0 * K;
    const long long lim = (long long)n * K;
    for (int idx = tid * 4; idx < 64 * K; idx += 1024) {
        float4 v = make_float4(0.f, 0.f, 0.f, 0.f);
        long long g = base + idx;
        if (g + 3 < lim) v = *(const float4*)&X[g];
        int row = idx / K, col = idx % K;
        *(float4*)&xs[row][col] = v;
    }
    __syncthreads();

    const int tc = tid & 15;
    const int tn = tid >> 4;
    float acc[4][4];
#pragma unroll
    for (int r = 0; r < 4; ++r)
#pragma unroll
        for (int c = 0; c < 4; ++c) acc[r][c] = 0.f;

#pragma unroll 4
    for (int k = 0; k < K; ++k) {
        float4 w = *(const float4*)&ws[k][tc * 4];
        float x0 = xs[4 * tn + 0][k];
        float x1 = xs[4 * tn + 1][k];
        float x2 = xs[4 * tn + 2][k];
        float x3 = xs[4 * tn + 3][k];
        acc[0][0] += x0 * w.x; acc[0][1] += x0 * w.y; acc[0][2] += x0 * w.z; acc[0][3] += x0 * w.w;
        acc[1][0] += x1 * w.x; acc[1][1] += x1 * w.y; acc[1][2] += x1 * w.z; acc[1][3] += x1 * w.w;
        acc[2][0] += x2 * w.x; acc[2][1] += x2 * w.y; acc[2][2] += x2 * w.z; acc[2][3] += x2 * w.w;
        acc[3][0] += x3 * w.x; acc[3][1] += x3 * w.y; acc[3][2] += x3 * w.z; acc[3][3] += x3 * w.w;
    }

#pragma unroll
    for (int r = 0; r < 4; ++r) {
        int node = n0 + 4 * tn + r;
        if (node < n) {
            float dv = dinv[node];
            float4 o;
            o.x = acc[r][0] * dv; o.y = acc[r][1] * dv; o.z = acc[r][2] * dv; o.w = acc[r][3] * dv;
            *(float4*)&out[(long long)node * NH + tc * 4] = o;
        }
    }
}

// ---------------- aggregation: one wave per node, lane = feature ----------------
// out[i] = relu(dinv[i] * (hs[i] + sum_{e:dst=i} hs[src_e]) + b) [+ resid[i]]

__global__ __launch_bounds__(256) void k_agg(const float* __restrict__ hs, const float* __restrict__ dinv,
                                             const int* __restrict__ rowptr, const int* __restrict__ csrc,
                                             const float* __restrict__ bias, const float* __restrict__ resid,
                                             float* __restrict__ out, int n) {
    int node = (int)((blockIdx.x * 256 + threadIdx.x) >> 6);
    int lane = threadIdx.x & 63;
    if (node >= n) return;
    long long rowbase = (long long)node * NH;
    float acc = hs[rowbase + lane];  // self loop
    int e0 = rowptr[node], e1 = rowptr[node + 1];
    for (int e = e0; e < e1; ++e) {
        int s = csrc[e];
        acc += hs[(long long)s * NH + lane];
    }
    float v = dinv[node] * acc + bias[lane];
    v = fmaxf(v, 0.f);
    if (resid) v += resid[rowbase + lane];
    out[rowbase + lane] = v;
}

// ---------------- launch ----------------

extern "C" void kernel_launch(void* const* d_in, const int* in_sizes, int n_in,
                              void* d_out, int out_size, void* d_ws, size_t ws_size,
                              hipStream_t stream) {
    const float* x  = (const float*)d_in[0];
    const int*   ei = (const int*)d_in[1];
    const float* W1 = (const float*)d_in[2];
    const float* b1 = (const float*)d_in[3];
    const float* W2 = (const float*)d_in[4];
    const float* b2 = (const float*)d_in[5];
    float* out = (float*)d_out;

    const int N = N_NODES;
    const int E = in_sizes[1] / 2;
    const int* src = ei;
    const int* dst = ei + E;

    // workspace layout (element offsets, all 16B-aligned)
    const int NP = 100352;  // padded N
    int*   cnt    = (int*)d_ws;
    int*   rowptr = cnt + NP;
    int*   cursor = rowptr + NP;
    float* dinv   = (float*)(cursor + NP);
    int*   bsum   = (int*)(dinv + NP);     // 512 ints
    int*   csrc   = bsum + 512;
    float* hs     = (float*)(csrc + 1600000);
    float* h1     = hs + (long long)N * NH;   // 6.4M floats each

    const int nb_n = (N + 255) / 256;
    const int nb_e = (E + 255) / 256;
    const int nb_scan = (N + 1023) / 1024;   // 98

    k_zero<<<nb_n, 256, 0, stream>>>(cnt, N);
    k_hist<<<nb_e, 256, 0, stream>>>(dst, cnt, E);
    k_scan_local<<<nb_scan, 256, 0, stream>>>(cnt, rowptr, bsum, N);
    k_scan_bsum<<<1, 256, 0, stream>>>(bsum, nb_scan);
    k_prep<<<(N + 256) / 256, 256, 0, stream>>>(cnt, rowptr, bsum, dinv, cursor, N, nb_scan);
    k_fill<<<nb_e, 256, 0, stream>>>(src, dst, cursor, csrc, E);

    // layer 1
    k_gemm_scale<128><<<(N + 63) / 64, 256, 0, stream>>>(x, W1, dinv, hs, N);
    k_agg<<<(N + 3) / 4, 256, 0, stream>>>(hs, dinv, rowptr, csrc, b1, nullptr, h1, N);

    // layer 2 (+ residual h1)
    k_gemm_scale<64><<<(N + 63) / 64, 256, 0, stream>>>(h1, W2, dinv, hs, N);
    k_agg<<<(N + 3) / 4, 256, 0, stream>>>(hs, dinv, rowptr, csrc, b2, h1, out, N);
}

// Round 4
// 363.603 us; speedup vs baseline: 2.2303x; 1.5055x over previous
//
#include <hip/hip_runtime.h>

#define N_NODES 100000
#define NH 64

// ---------------- graph preprocessing ----------------

__global__ __launch_bounds__(256) void k_zero(int* __restrict__ cnt, int n) {
    int i = blockIdx.x * 256 + threadIdx.x;
    if (i < n) cnt[i] = 0;
}

__global__ __launch_bounds__(256) void k_hist(const int* __restrict__ dst, int* __restrict__ cnt, int e) {
    int i = blockIdx.x * 256 + threadIdx.x;
    if (i < e) atomicAdd(&cnt[dst[i]], 1);
}

// hierarchical scan, level 1
__global__ __launch_bounds__(256) void k_scan_local(const int* __restrict__ cnt, int* __restrict__ rowptr,
                                                    int* __restrict__ bsum, int n) {
    __shared__ int wsum[4];
    const int t = threadIdx.x;
    const int lane = t & 63, wave = t >> 6;
    const int base = blockIdx.x * 1024 + t * 4;
    int v0 = 0, v1 = 0, v2 = 0, v3 = 0;
    if (base + 3 < n) {
        int4 c = *(const int4*)&cnt[base];
        v0 = c.x; v1 = c.y; v2 = c.z; v3 = c.w;
    } else {
        if (base + 0 < n) v0 = cnt[base + 0];
        if (base + 1 < n) v1 = cnt[base + 1];
        if (base + 2 < n) v2 = cnt[base + 2];
    }
    const int s = v0 + v1 + v2 + v3;
    int inc = s;
#pragma unroll
    for (int d = 1; d < 64; d <<= 1) {
        int u = __shfl_up(inc, d, 64);
        if (lane >= d) inc += u;
    }
    if (lane == 63) wsum[wave] = inc;
    __syncthreads();
    int woff = 0;
#pragma unroll
    for (int w = 0; w < 4; ++w)
        if (w < wave) woff += wsum[w];
    int excl = woff + inc - s;
    if (base + 0 < n) rowptr[base + 0] = excl; excl += v0;
    if (base + 1 < n) rowptr[base + 1] = excl; excl += v1;
    if (base + 2 < n) rowptr[base + 2] = excl; excl += v2;
    if (base + 3 < n) rowptr[base + 3] = excl;
    if (t == 255) bsum[blockIdx.x] = woff + inc;
}

// level 2
__global__ __launch_bounds__(256) void k_scan_bsum(int* __restrict__ bsum, int nb) {
    __shared__ int wsum[4];
    const int t = threadIdx.x;
    const int lane = t & 63, wave = t >> 6;
    const int v = (t < nb) ? bsum[t] : 0;
    int inc = v;
#pragma unroll
    for (int d = 1; d < 64; d <<= 1) {
        int u = __shfl_up(inc, d, 64);
        if (lane >= d) inc += u;
    }
    if (lane == 63) wsum[wave] = inc;
    __syncthreads();
    int woff = 0;
#pragma unroll
    for (int w = 0; w < 4; ++w)
        if (w < wave) woff += wsum[w];
    if (t < nb) bsum[t] = woff + inc - v;
    if (t == 255) bsum[nb] = woff + inc;
}

// level 3 fused with prep
__global__ __launch_bounds__(256) void k_prep(const int* __restrict__ cnt, int* __restrict__ rowptr,
                                              const int* __restrict__ bsum, float* __restrict__ dinv,
                                              int* __restrict__ cursor, int n, int nb) {
    int i = blockIdx.x * 256 + threadIdx.x;
    if (i < n) {
        int rp = rowptr[i] + bsum[i >> 10];
        rowptr[i] = rp;
        cursor[i] = rp;
        dinv[i] = rsqrtf((float)(cnt[i] + 1));
    }
    if (i == n) rowptr[n] = bsum[nb];
}

__global__ __launch_bounds__(256) void k_fill(const int* __restrict__ src, const int* __restrict__ dst,
                                              int* __restrict__ cursor, int* __restrict__ csrc, int e) {
    int i = blockIdx.x * 256 + threadIdx.x;
    if (i < e) {
        int d = dst[i];
        int pos = atomicAdd(&cursor[d], 1);
        csrc[pos] = src[i];
    }
}

// ---------------- bf16 helpers (raw bits; RNE rounding) ----------------

__device__ __forceinline__ unsigned short f2bf(float f) {
    union { float f; unsigned int i; } c;
    c.f = f;
    unsigned int b = c.i;
    b += 0x7FFFu + ((b >> 16) & 1u);   // round to nearest even
    return (unsigned short)(b >> 16);
}

__device__ __forceinline__ float bf2f(unsigned short u) {
    union { unsigned int i; float f; } c;
    c.i = ((unsigned int)u) << 16;
    return c.f;
}

// ---------------- GEMM: hs[node][c] = bf16( (sum_k X[node][k]*W[k][c]) * dinv[node] ) ----------

template <int K>
__global__ __launch_bounds__(256) void k_gemm_scale(const float* __restrict__ X, const float* __restrict__ W,
                                                    const float* __restrict__ dinv,
                                                    unsigned short* __restrict__ out, int n) {
    __shared__ float xs[64][132];
    __shared__ float ws[K][64];
    const int tid = threadIdx.x;
    const int n0 = blockIdx.x * 64;

    float* wsf = &ws[0][0];
    for (int idx = tid * 4; idx < K * 64; idx += 1024) {
        *(float4*)&wsf[idx] = *(const float4*)&W[idx];
    }
    const long long base = (long long)n0 * K;
    const long long lim = (long long)n * K;
    for (int idx = tid * 4; idx < 64 * K; idx += 1024) {
        float4 v = make_float4(0.f, 0.f, 0.f, 0.f);
        long long g = base + idx;
        if (g + 3 < lim) v = *(const float4*)&X[g];
        int row = idx / K, col = idx % K;
        *(float4*)&xs[row][col] = v;
    }
    __syncthreads();

    const int tc = tid & 15;
    const int tn = tid >> 4;
    float acc[4][4];
#pragma unroll
    for (int r = 0; r < 4; ++r)
#pragma unroll
        for (int c = 0; c < 4; ++c) acc[r][c] = 0.f;

#pragma unroll 4
    for (int k = 0; k < K; ++k) {
        float4 w = *(const float4*)&ws[k][tc * 4];
        float x0 = xs[4 * tn + 0][k];
        float x1 = xs[4 * tn + 1][k];
        float x2 = xs[4 * tn + 2][k];
        float x3 = xs[4 * tn + 3][k];
        acc[0][0] += x0 * w.x; acc[0][1] += x0 * w.y; acc[0][2] += x0 * w.z; acc[0][3] += x0 * w.w;
        acc[1][0] += x1 * w.x; acc[1][1] += x1 * w.y; acc[1][2] += x1 * w.z; acc[1][3] += x1 * w.w;
        acc[2][0] += x2 * w.x; acc[2][1] += x2 * w.y; acc[2][2] += x2 * w.z; acc[2][3] += x2 * w.w;
        acc[3][0] += x3 * w.x; acc[3][1] += x3 * w.y; acc[3][2] += x3 * w.z; acc[3][3] += x3 * w.w;
    }

#pragma unroll
    for (int r = 0; r < 4; ++r) {
        int node = n0 + 4 * tn + r;
        if (node < n) {
            float dv = dinv[node];
            ushort4 o;
            o.x = f2bf(acc[r][0] * dv);
            o.y = f2bf(acc[r][1] * dv);
            o.z = f2bf(acc[r][2] * dv);
            o.w = f2bf(acc[r][3] * dv);
            *(ushort4*)&out[(long long)node * NH + tc * 4] = o;
        }
    }
}

// ---------------- aggregation: one wave per node, lane = feature ----------------
// out[i] = relu(dinv[i] * (hs[i] + sum_{e:dst=i} hs[src_e]) + b) [+ resid[i]]
// hs is bf16 (pre-scaled by dinv[src]); 4-way unrolled gather, scalar edge loads.

__global__ __launch_bounds__(256) void k_agg(const unsigned short* __restrict__ hs, const float* __restrict__ dinv,
                                             const int* __restrict__ rowptr, const int* __restrict__ csrc,
                                             const float* __restrict__ bias, const float* __restrict__ resid,
                                             float* __restrict__ out, int n) {
    int node = (int)((blockIdx.x * 256 + threadIdx.x) >> 6);
    int lane = threadIdx.x & 63;
    if (node >= n) return;
    node = __builtin_amdgcn_readfirstlane(node);  // wave-uniform -> scalar loads below
    long long rowbase = (long long)node * NH;
    float a0 = bf2f(hs[rowbase + lane]);  // self loop
    float a1 = 0.f, a2 = 0.f, a3 = 0.f;
    const int e0 = rowptr[node], e1 = rowptr[node + 1];
    int e = e0;
    for (; e + 4 <= e1; e += 4) {
        int s0 = csrc[e + 0];
        int s1 = csrc[e + 1];
        int s2 = csrc[e + 2];
        int s3 = csrc[e + 3];
        a0 += bf2f(hs[(long long)s0 * NH + lane]);
        a1 += bf2f(hs[(long long)s1 * NH + lane]);
        a2 += bf2f(hs[(long long)s2 * NH + lane]);
        a3 += bf2f(hs[(long long)s3 * NH + lane]);
    }
    for (; e < e1; ++e) {
        int s = csrc[e];
        a0 += bf2f(hs[(long long)s * NH + lane]);
    }
    float acc = (a0 + a1) + (a2 + a3);
    float v = dinv[node] * acc + bias[lane];
    v = fmaxf(v, 0.f);
    if (resid) v += resid[rowbase + lane];
    out[rowbase + lane] = v;
}

// ---------------- launch ----------------

extern "C" void kernel_launch(void* const* d_in, const int* in_sizes, int n_in,
                              void* d_out, int out_size, void* d_ws, size_t ws_size,
                              hipStream_t stream) {
    const float* x  = (const float*)d_in[0];
    const int*   ei = (const int*)d_in[1];
    const float* W1 = (const float*)d_in[2];
    const float* b1 = (const float*)d_in[3];
    const float* W2 = (const float*)d_in[4];
    const float* b2 = (const float*)d_in[5];
    float* out = (float*)d_out;

    const int N = N_NODES;
    const int E = in_sizes[1] / 2;
    const int* src = ei;
    const int* dst = ei + E;

    // workspace layout (element offsets, all 16B-aligned)
    const int NP = 100352;  // padded N
    int*   cnt    = (int*)d_ws;
    int*   rowptr = cnt + NP;
    int*   cursor = rowptr + NP;
    float* dinv   = (float*)(cursor + NP);
    int*   bsum   = (int*)(dinv + NP);     // 512 ints
    int*   csrc   = bsum + 512;
    unsigned short* hsb = (unsigned short*)(csrc + 1600000);   // bf16 [N][64]
    float* h1     = (float*)(hsb + (long long)NP * NH);        // fp32 [N][64]

    const int nb_n = (N + 255) / 256;
    const int nb_e = (E + 255) / 256;
    const int nb_scan = (N + 1023) / 1024;   // 98

    k_zero<<<nb_n, 256, 0, stream>>>(cnt, N);
    k_hist<<<nb_e, 256, 0, stream>>>(dst, cnt, E);
    k_scan_local<<<nb_scan, 256, 0, stream>>>(cnt, rowptr, bsum, N);
    k_scan_bsum<<<1, 256, 0, stream>>>(bsum, nb_scan);
    k_prep<<<(N + 256) / 256, 256, 0, stream>>>(cnt, rowptr, bsum, dinv, cursor, N, nb_scan);
    k_fill<<<nb_e, 256, 0, stream>>>(src, dst, cursor, csrc, E);

    // layer 1
    k_gemm_scale<128><<<(N + 63) / 64, 256, 0, stream>>>(x, W1, dinv, hsb, N);
    k_agg<<<(N + 3) / 4, 256, 0, stream>>>(hsb, dinv, rowptr, csrc, b1, nullptr, h1, N);

    // layer 2 (+ residual h1)
    k_gemm_scale<64><<<(N + 63) / 64, 256, 0, stream>>>(h1, W2, dinv, hsb, N);
    k_agg<<<(N + 3) / 4, 256, 0, stream>>>(hsb, dinv, rowptr, csrc, b2, h1, out, N);
}

// Round 5
// 247.646 us; speedup vs baseline: 3.2746x; 1.4682x over previous
//
#include <hip/hip_runtime.h>

#define N_NODES 100000
#define NH 64
#define NB 512          // buckets
#define NPB 196         // nodes per bucket (512*196 = 100352 >= N)
#define BCAP 4096       // bucket capacity (avg 3131, +17 sigma)

// ---------------- bf16 helpers (raw bits; RNE rounding) ----------------

__device__ __forceinline__ unsigned short f2bf(float f) {
    union { float f; unsigned int i; } c;
    c.f = f;
    unsigned int b = c.i;
    b += 0x7FFFu + ((b >> 16) & 1u);   // round to nearest even
    return (unsigned short)(b >> 16);
}

__device__ __forceinline__ float bf2f(unsigned short u) {
    union { unsigned int i; float f; } c;
    c.i = ((unsigned int)u) << 16;
    return c.f;
}

// ---------------- CSR build via bucketed counting sort ----------------

__global__ __launch_bounds__(256) void k_zero(int* __restrict__ p, int n) {
    int i = blockIdx.x * 256 + threadIdx.x;
    if (i < n) p[i] = 0;
}

// scatter edges into 512 buckets; pack (dst_local<<17)|src in u32
__global__ __launch_bounds__(256) void k_scatter(const int* __restrict__ src, const int* __restrict__ dst,
                                                 int* __restrict__ bcur, unsigned* __restrict__ ebuf, int e) {
    int i = blockIdx.x * 256 + threadIdx.x;
    if (i >= e) return;
    int d = dst[i];
    int s = src[i];
    int b = d / NPB;
    int dl = d - b * NPB;
    int pos = atomicAdd(&bcur[b * 16], 1);          // cursors padded: 1 per 64B line
    if (pos < BCAP) ebuf[b * BCAP + pos] = ((unsigned)dl << 17) | (unsigned)s;
}

// single block: exclusive scan of 512 bucket counts -> bstart; rowptr[N] = total
__global__ __launch_bounds__(512) void k_bscan(const int* __restrict__ bcur, int* __restrict__ bstart,
                                               int* __restrict__ rowptr_n) {
    __shared__ int wsum[8];
    const int t = threadIdx.x, lane = t & 63, wave = t >> 6;
    const int v = bcur[t * 16];
    int inc = v;
#pragma unroll
    for (int d = 1; d < 64; d <<= 1) {
        int u = __shfl_up(inc, d, 64);
        if (lane >= d) inc += u;
    }
    if (lane == 63) wsum[wave] = inc;
    __syncthreads();
    int woff = 0;
#pragma unroll
    for (int w = 0; w < 8; ++w)
        if (w < wave) woff += wsum[w];
    bstart[t] = woff + inc - v;
    if (t == 511) *rowptr_n = woff + inc;
}

// one block per bucket: local hist + scan -> rowptr/dinv, then L2-hot scatter into csrc
__global__ __launch_bounds__(256) void k_build(const unsigned* __restrict__ ebuf, const int* __restrict__ bcur,
                                               const int* __restrict__ bstart, int* __restrict__ rowptr,
                                               float* __restrict__ dinv, int* __restrict__ csrc, int n) {
    __shared__ unsigned ls[BCAP];
    __shared__ int lh[256];
    __shared__ int lc[256];
    __shared__ int wsum[4];
    const int b = blockIdx.x;
    const int t = threadIdx.x;
    const int node0 = b * NPB;
    int count = bcur[b * 16];
    if (count > BCAP) count = BCAP;
    const int base = bstart[b];

    lh[t] = 0;
    for (int i = t; i < count; i += 256) ls[i] = ebuf[b * BCAP + i];
    __syncthreads();
    for (int i = t; i < count; i += 256) atomicAdd(&lh[ls[i] >> 17], 1);
    __syncthreads();

    const int lane = t & 63, wave = t >> 6;
    const int v = lh[t];
    int inc = v;
#pragma unroll
    for (int d = 1; d < 64; d <<= 1) {
        int u = __shfl_up(inc, d, 64);
        if (lane >= d) inc += u;
    }
    if (lane == 63) wsum[wave] = inc;
    __syncthreads();
    int woff = 0;
#pragma unroll
    for (int w = 0; w < 4; ++w)
        if (w < wave) woff += wsum[w];
    const int excl = woff + inc - v;

    lc[t] = base + excl;
    const int node = node0 + t;
    if (t < NPB && node < n) {
        rowptr[node] = base + excl;
        dinv[node] = rsqrtf((float)(v + 1));   // +1 self loop
    }
    __syncthreads();

    for (int i = t; i < count; i += 256) {
        unsigned u = ls[i];
        int pos = atomicAdd(&lc[u >> 17], 1);
        csrc[pos] = (int)(u & 0x1FFFFu);
    }
}

// ---------------- GEMM: hs[node][c] = bf16( (sum_k X[node][k]*W[k][c]) * dinv[node] ) ----------

template <int K>
__global__ __launch_bounds__(256) void k_gemm_scale(const float* __restrict__ X, const float* __restrict__ W,
                                                    const float* __restrict__ dinv,
                                                    unsigned short* __restrict__ out, int n) {
    __shared__ float xs[64][132];
    __shared__ float ws[K][64];
    const int tid = threadIdx.x;
    const int n0 = blockIdx.x * 64;

    float* wsf = &ws[0][0];
    for (int idx = tid * 4; idx < K * 64; idx += 1024) {
        *(float4*)&wsf[idx] = *(const float4*)&W[idx];
    }
    const long long base = (long long)n0 * K;
    const long long lim = (long long)n * K;
    for (int idx = tid * 4; idx < 64 * K; idx += 1024) {
        float4 v = make_float4(0.f, 0.f, 0.f, 0.f);
        long long g = base + idx;
        if (g + 3 < lim) v = *(const float4*)&X[g];
        int row = idx / K, col = idx % K;
        *(float4*)&xs[row][col] = v;
    }
    __syncthreads();

    const int tc = tid & 15;
    const int tn = tid >> 4;
    float acc[4][4];
#pragma unroll
    for (int r = 0; r < 4; ++r)
#pragma unroll
        for (int c = 0; c < 4; ++c) acc[r][c] = 0.f;

#pragma unroll 4
    for (int k = 0; k < K; ++k) {
        float4 w = *(const float4*)&ws[k][tc * 4];
        float x0 = xs[4 * tn + 0][k];
        float x1 = xs[4 * tn + 1][k];
        float x2 = xs[4 * tn + 2][k];
        float x3 = xs[4 * tn + 3][k];
        acc[0][0] += x0 * w.x; acc[0][1] += x0 * w.y; acc[0][2] += x0 * w.z; acc[0][3] += x0 * w.w;
        acc[1][0] += x1 * w.x; acc[1][1] += x1 * w.y; acc[1][2] += x1 * w.z; acc[1][3] += x1 * w.w;
        acc[2][0] += x2 * w.x; acc[2][1] += x2 * w.y; acc[2][2] += x2 * w.z; acc[2][3] += x2 * w.w;
        acc[3][0] += x3 * w.x; acc[3][1] += x3 * w.y; acc[3][2] += x3 * w.z; acc[3][3] += x3 * w.w;
    }

#pragma unroll
    for (int r = 0; r < 4; ++r) {
        int node = n0 + 4 * tn + r;
        if (node < n) {
            float dv = dinv[node];
            ushort4 o;
            o.x = f2bf(acc[r][0] * dv);
            o.y = f2bf(acc[r][1] * dv);
            o.z = f2bf(acc[r][2] * dv);
            o.w = f2bf(acc[r][3] * dv);
            *(ushort4*)&out[(long long)node * NH + tc * 4] = o;
        }
    }
}

// ---------------- aggregation: one wave per node, lane = feature ----------------

__global__ __launch_bounds__(256) void k_agg(const unsigned short* __restrict__ hs, const float* __restrict__ dinv,
                                             const int* __restrict__ rowptr, const int* __restrict__ csrc,
                                             const float* __restrict__ bias, const float* __restrict__ resid,
                                             float* __restrict__ out, int n) {
    int node = (int)((blockIdx.x * 256 + threadIdx.x) >> 6);
    int lane = threadIdx.x & 63;
    if (node >= n) return;
    node = __builtin_amdgcn_readfirstlane(node);  // wave-uniform -> scalar loads
    long long rowbase = (long long)node * NH;
    float a0 = bf2f(hs[rowbase + lane]);  // self loop
    float a1 = 0.f, a2 = 0.f, a3 = 0.f;
    const int e0 = rowptr[node], e1 = rowptr[node + 1];
    int e = e0;
    for (; e + 4 <= e1; e += 4) {
        int s0 = csrc[e + 0];
        int s1 = csrc[e + 1];
        int s2 = csrc[e + 2];
        int s3 = csrc[e + 3];
        a0 += bf2f(hs[(long long)s0 * NH + lane]);
        a1 += bf2f(hs[(long long)s1 * NH + lane]);
        a2 += bf2f(hs[(long long)s2 * NH + lane]);
        a3 += bf2f(hs[(long long)s3 * NH + lane]);
    }
    for (; e < e1; ++e) {
        int s = csrc[e];
        a0 += bf2f(hs[(long long)s * NH + lane]);
    }
    float acc = (a0 + a1) + (a2 + a3);
    float v = dinv[node] * acc + bias[lane];
    v = fmaxf(v, 0.f);
    if (resid) v += resid[rowbase + lane];
    out[rowbase + lane] = v;
}

// ---------------- launch ----------------

extern "C" void kernel_launch(void* const* d_in, const int* in_sizes, int n_in,
                              void* d_out, int out_size, void* d_ws, size_t ws_size,
                              hipStream_t stream) {
    const float* x  = (const float*)d_in[0];
    const int*   ei = (const int*)d_in[1];
    const float* W1 = (const float*)d_in[2];
    const float* b1 = (const float*)d_in[3];
    const float* W2 = (const float*)d_in[4];
    const float* b2 = (const float*)d_in[5];
    float* out = (float*)d_out;

    const int N = N_NODES;
    const int E = in_sizes[1] / 2;
    const int* src = ei;
    const int* dst = ei + E;

    // workspace layout (element offsets, 16B-aligned). ebuf aliases hsb:
    // ebuf is dead after k_build; gemm1 (stream-ordered later) overwrites it.
    const int NP = 100352;  // padded N (= NB*NPB)
    int*   bcur   = (int*)d_ws;                    // 512*16 padded cursors
    int*   bstart = bcur + NB * 16;                // 512
    int*   rowptr = bstart + NB;                   // N+1 (padded to NP)
    float* dinv   = (float*)(rowptr + NP);         // NP
    int*   csrc   = (int*)(dinv + NP);             // E (padded)
    unsigned* ebuf = (unsigned*)(csrc + 1600512);  // NB*BCAP = 2M u32 (8.4MB)
    unsigned short* hsb = (unsigned short*)ebuf;   // bf16 [NP][64] = 12.8MB (aliases ebuf)
    float* h1     = (float*)(hsb + (long long)NP * NH);  // fp32 [N][64]

    const int nb_e = (E + 255) / 256;

    k_zero<<<(NB * 16 + 255) / 256, 256, 0, stream>>>(bcur, NB * 16);
    k_scatter<<<nb_e, 256, 0, stream>>>(src, dst, bcur, ebuf, E);
    k_bscan<<<1, 512, 0, stream>>>(bcur, bstart, rowptr + N);
    k_build<<<NB, 256, 0, stream>>>(ebuf, bcur, bstart, rowptr, dinv, csrc, N);

    // layer 1
    k_gemm_scale<128><<<(N + 63) / 64, 256, 0, stream>>>(x, W1, dinv, hsb, N);
    k_agg<<<(N + 3) / 4, 256, 0, stream>>>(hsb, dinv, rowptr, csrc, b1, nullptr, h1, N);

    // layer 2 (+ residual h1)
    k_gemm_scale<64><<<(N + 63) / 64, 256, 0, stream>>>(h1, W2, dinv, hsb, N);
    k_agg<<<(N + 3) / 4, 256, 0, stream>>>(hsb, dinv, rowptr, csrc, b2, h1, out, N);
}

// Round 6
// 241.499 us; speedup vs baseline: 3.3579x; 1.0255x over previous
//
#include <hip/hip_runtime.h>

#define N_NODES 100000
#define NH 64
#define NB 512          // buckets
#define NPB 196         // nodes per bucket (512*196 = 100352 >= N)
#define NSB 8           // sub-buckets per bucket (XCD-local write streams)
#define SBCAP 768       // capacity per (bucket, sub): avg 391, +19 sigma
#define BCAP 4096       // max edges per bucket staged in LDS (avg 3131)

// ---------------- bf16 helpers (raw bits; RNE rounding) ----------------

__device__ __forceinline__ unsigned short f2bf(float f) {
    union { float f; unsigned int i; } c;
    c.f = f;
    unsigned int b = c.i;
    b += 0x7FFFu + ((b >> 16) & 1u);   // round to nearest even
    return (unsigned short)(b >> 16);
}

__device__ __forceinline__ float bf2f(unsigned short u) {
    union { unsigned int i; float f; } c;
    c.i = ((unsigned int)u) << 16;
    return c.f;
}

// ---------------- CSR build via bucketed counting sort ----------------

__global__ __launch_bounds__(256) void k_zero(int* __restrict__ p, int n) {
    int i = blockIdx.x * 256 + threadIdx.x;
    if (i < n) p[i] = 0;
}

// scatter edges into (bucket, xcd-hint) cells; pack (dst_local<<17)|src in u32.
// blockIdx&7 keys the sub-bucket: with round-robin block->XCD dispatch, each
// cell's frontier line is written by ONE XCD's L2 -> full write combining.
__global__ __launch_bounds__(256) void k_scatter(const int* __restrict__ src, const int* __restrict__ dst,
                                                 int* __restrict__ bcur, unsigned* __restrict__ ebuf, int e) {
    int i = blockIdx.x * 256 + threadIdx.x;
    if (i >= e) return;
    int sb = blockIdx.x & (NSB - 1);
    int d = dst[i];
    int s = src[i];
    int b = d / NPB;
    int dl = d - b * NPB;
    int cell = b * NSB + sb;
    int pos = atomicAdd(&bcur[cell * 16], 1);       // cursors padded: 1 per 64B line
    if (pos < SBCAP) ebuf[(long long)cell * SBCAP + pos] = ((unsigned)dl << 17) | (unsigned)s;
}

// single block: per-bucket total = sum of 8 sub-counts; exclusive scan -> bstart; rowptr[N] = E
__global__ __launch_bounds__(512) void k_bscan(const int* __restrict__ bcur, int* __restrict__ bstart,
                                               int* __restrict__ rowptr_n) {
    __shared__ int wsum[8];
    const int t = threadIdx.x, lane = t & 63, wave = t >> 6;
    int v = 0;
#pragma unroll
    for (int s = 0; s < NSB; ++s) {
        int c = bcur[(t * NSB + s) * 16];
        v += (c < SBCAP) ? c : SBCAP;
    }
    int inc = v;
#pragma unroll
    for (int d = 1; d < 64; d <<= 1) {
        int u = __shfl_up(inc, d, 64);
        if (lane >= d) inc += u;
    }
    if (lane == 63) wsum[wave] = inc;
    __syncthreads();
    int woff = 0;
#pragma unroll
    for (int w = 0; w < 8; ++w)
        if (w < wave) woff += wsum[w];
    bstart[t] = woff + inc - v;
    if (t == 511) *rowptr_n = woff + inc;
}

// one block per bucket: concat 8 sub-segments in LDS, hist + scan -> rowptr/dinv,
// then L2-hot scatter into the bucket's contiguous csrc slice.
__global__ __launch_bounds__(256) void k_build(const unsigned* __restrict__ ebuf, const int* __restrict__ bcur,
                                               const int* __restrict__ bstart, int* __restrict__ rowptr,
                                               float* __restrict__ dinv, int* __restrict__ csrc, int n) {
    __shared__ unsigned ls[BCAP];
    __shared__ int lh[256];
    __shared__ int lc[256];
    __shared__ int wsum[4];
    const int b = blockIdx.x;
    const int t = threadIdx.x;
    const int node0 = b * NPB;
    const int base = bstart[b];

    lh[t] = 0;
    int off = 0;
#pragma unroll
    for (int s = 0; s < NSB; ++s) {
        int c = bcur[(b * NSB + s) * 16];
        if (c > SBCAP) c = SBCAP;
        const unsigned* seg = &ebuf[(long long)(b * NSB + s) * SBCAP];
        for (int i = t; i < c; i += 256) ls[off + i] = seg[i];
        off += c;
    }
    const int count = off;
    __syncthreads();
    for (int i = t; i < count; i += 256) atomicAdd(&lh[ls[i] >> 17], 1);
    __syncthreads();

    const int lane = t & 63, wave = t >> 6;
    const int v = lh[t];
    int inc = v;
#pragma unroll
    for (int d = 1; d < 64; d <<= 1) {
        int u = __shfl_up(inc, d, 64);
        if (lane >= d) inc += u;
    }
    if (lane == 63) wsum[wave] = inc;
    __syncthreads();
    int woff = 0;
#pragma unroll
    for (int w = 0; w < 4; ++w)
        if (w < wave) woff += wsum[w];
    const int excl = woff + inc - v;

    lc[t] = base + excl;
    const int node = node0 + t;
    if (t < NPB && node < n) {
        rowptr[node] = base + excl;
        dinv[node] = rsqrtf((float)(v + 1));   // +1 self loop
    }
    __syncthreads();

    for (int i = t; i < count; i += 256) {
        unsigned u = ls[i];
        int pos = atomicAdd(&lc[u >> 17], 1);
        csrc[pos] = (int)(u & 0x1FFFFu);
    }
}

// ---------------- GEMM: hs[node][c] = bf16( (sum_k X[node][k]*W[k][c]) * dinv[node] ) ----------

template <int K>
__global__ __launch_bounds__(256) void k_gemm_scale(const float* __restrict__ X, const float* __restrict__ W,
                                                    const float* __restrict__ dinv,
                                                    unsigned short* __restrict__ out, int n) {
    __shared__ float xs[64][132];
    __shared__ float ws[K][64];
    const int tid = threadIdx.x;
    const int n0 = blockIdx.x * 64;

    float* wsf = &ws[0][0];
    for (int idx = tid * 4; idx < K * 64; idx += 1024) {
        *(float4*)&wsf[idx] = *(const float4*)&W[idx];
    }
    const long long base = (long long)n0 * K;
    const long long lim = (long long)n * K;
    for (int idx = tid * 4; idx < 64 * K; idx += 1024) {
        float4 v = make_float4(0.f, 0.f, 0.f, 0.f);
        long long g = base + idx;
        if (g + 3 < lim) v = *(const float4*)&X[g];
        int row = idx / K, col = idx % K;
        *(float4*)&xs[row][col] = v;
    }
    __syncthreads();

    const int tc = tid & 15;
    const int tn = tid >> 4;
    float acc[4][4];
#pragma unroll
    for (int r = 0; r < 4; ++r)
#pragma unroll
        for (int c = 0; c < 4; ++c) acc[r][c] = 0.f;

#pragma unroll 4
    for (int k = 0; k < K; ++k) {
        float4 w = *(const float4*)&ws[k][tc * 4];
        float x0 = xs[4 * tn + 0][k];
        float x1 = xs[4 * tn + 1][k];
        float x2 = xs[4 * tn + 2][k];
        float x3 = xs[4 * tn + 3][k];
        acc[0][0] += x0 * w.x; acc[0][1] += x0 * w.y; acc[0][2] += x0 * w.z; acc[0][3] += x0 * w.w;
        acc[1][0] += x1 * w.x; acc[1][1] += x1 * w.y; acc[1][2] += x1 * w.z; acc[1][3] += x1 * w.w;
        acc[2][0] += x2 * w.x; acc[2][1] += x2 * w.y; acc[2][2] += x2 * w.z; acc[2][3] += x2 * w.w;
        acc[3][0] += x3 * w.x; acc[3][1] += x3 * w.y; acc[3][2] += x3 * w.z; acc[3][3] += x3 * w.w;
    }

#pragma unroll
    for (int r = 0; r < 4; ++r) {
        int node = n0 + 4 * tn + r;
        if (node < n) {
            float dv = dinv[node];
            ushort4 o;
            o.x = f2bf(acc[r][0] * dv);
            o.y = f2bf(acc[r][1] * dv);
            o.z = f2bf(acc[r][2] * dv);
            o.w = f2bf(acc[r][3] * dv);
            *(ushort4*)&out[(long long)node * NH + tc * 4] = o;
        }
    }
}

// ---------------- aggregation: one wave per node, lane = feature ----------------
// 8 independent accumulators -> 8 gathers in flight per wave.

__global__ __launch_bounds__(256) void k_agg(const unsigned short* __restrict__ hs, const float* __restrict__ dinv,
                                             const int* __restrict__ rowptr, const int* __restrict__ csrc,
                                             const float* __restrict__ bias, const float* __restrict__ resid,
                                             float* __restrict__ out, int n) {
    int node = (int)((blockIdx.x * 256 + threadIdx.x) >> 6);
    int lane = threadIdx.x & 63;
    if (node >= n) return;
    node = __builtin_amdgcn_readfirstlane(node);  // wave-uniform -> scalar CSR loads
    long long rowbase = (long long)node * NH;
    float a0 = bf2f(hs[rowbase + lane]);  // self loop
    float a1 = 0.f, a2 = 0.f, a3 = 0.f, a4 = 0.f, a5 = 0.f, a6 = 0.f, a7 = 0.f;
    const int e0 = rowptr[node], e1 = rowptr[node + 1];
    int e = e0;
    for (; e + 8 <= e1; e += 8) {
        int s0 = csrc[e + 0];
        int s1 = csrc[e + 1];
        int s2 = csrc[e + 2];
        int s3 = csrc[e + 3];
        int s4 = csrc[e + 4];
        int s5 = csrc[e + 5];
        int s6 = csrc[e + 6];
        int s7 = csrc[e + 7];
        a0 += bf2f(hs[(long long)s0 * NH + lane]);
        a1 += bf2f(hs[(long long)s1 * NH + lane]);
        a2 += bf2f(hs[(long long)s2 * NH + lane]);
        a3 += bf2f(hs[(long long)s3 * NH + lane]);
        a4 += bf2f(hs[(long long)s4 * NH + lane]);
        a5 += bf2f(hs[(long long)s5 * NH + lane]);
        a6 += bf2f(hs[(long long)s6 * NH + lane]);
        a7 += bf2f(hs[(long long)s7 * NH + lane]);
    }
    for (; e + 4 <= e1; e += 4) {
        int s0 = csrc[e + 0];
        int s1 = csrc[e + 1];
        int s2 = csrc[e + 2];
        int s3 = csrc[e + 3];
        a0 += bf2f(hs[(long long)s0 * NH + lane]);
        a1 += bf2f(hs[(long long)s1 * NH + lane]);
        a2 += bf2f(hs[(long long)s2 * NH + lane]);
        a3 += bf2f(hs[(long long)s3 * NH + lane]);
    }
    for (; e < e1; ++e) {
        int s = csrc[e];
        a0 += bf2f(hs[(long long)s * NH + lane]);
    }
    float acc = ((a0 + a1) + (a2 + a3)) + ((a4 + a5) + (a6 + a7));
    float v = dinv[node] * acc + bias[lane];
    v = fmaxf(v, 0.f);
    if (resid) v += resid[rowbase + lane];
    out[rowbase + lane] = v;
}

// ---------------- launch ----------------

extern "C" void kernel_launch(void* const* d_in, const int* in_sizes, int n_in,
                              void* d_out, int out_size, void* d_ws, size_t ws_size,
                              hipStream_t stream) {
    const float* x  = (const float*)d_in[0];
    const int*   ei = (const int*)d_in[1];
    const float* W1 = (const float*)d_in[2];
    const float* b1 = (const float*)d_in[3];
    const float* W2 = (const float*)d_in[4];
    const float* b2 = (const float*)d_in[5];
    float* out = (float*)d_out;

    const int N = N_NODES;
    const int E = in_sizes[1] / 2;
    const int* src = ei;
    const int* dst = ei + E;

    // workspace layout (element offsets, 16B-aligned). ebuf aliases hsb:
    // ebuf (12.6MB) is dead after k_build; gemm1 overwrites the region (stream-ordered).
    const int NP = 100352;  // padded N (= NB*NPB)
    int*   bcur   = (int*)d_ws;                    // NB*NSB*16 padded cursors (256KB)
    int*   bstart = bcur + NB * NSB * 16;          // 512
    int*   rowptr = bstart + NB;                   // N+1 (padded to NP)
    float* dinv   = (float*)(rowptr + NP);         // NP
    int*   csrc   = (int*)(dinv + NP);             // E (padded)
    unsigned* ebuf = (unsigned*)(csrc + 1600512);  // NB*NSB*SBCAP u32 = 12.6MB
    unsigned short* hsb = (unsigned short*)ebuf;   // bf16 [NP][64] = 12.8MB (aliases ebuf)
    float* h1     = (float*)(hsb + (long long)NP * NH);  // fp32 [N][64]

    const int nb_e = (E + 255) / 256;

    k_zero<<<(NB * NSB * 16 + 255) / 256, 256, 0, stream>>>(bcur, NB * NSB * 16);
    k_scatter<<<nb_e, 256, 0, stream>>>(src, dst, bcur, ebuf, E);
    k_bscan<<<1, 512, 0, stream>>>(bcur, bstart, rowptr + N);
    k_build<<<NB, 256, 0, stream>>>(ebuf, bcur, bstart, rowptr, dinv, csrc, N);

    // layer 1
    k_gemm_scale<128><<<(N + 63) / 64, 256, 0, stream>>>(x, W1, dinv, hsb, N);
    k_agg<<<(N + 3) / 4, 256, 0, stream>>>(hsb, dinv, rowptr, csrc, b1, nullptr, h1, N);

    // layer 2 (+ residual h1)
    k_gemm_scale<64><<<(N + 63) / 64, 256, 0, stream>>>(h1, W2, dinv, hsb, N);
    k_agg<<<(N + 3) / 4, 256, 0, stream>>>(hsb, dinv, rowptr, csrc, b2, h1, out, N);
}

// Round 7
// 199.848 us; speedup vs baseline: 4.0578x; 1.2084x over previous
//
#include <hip/hip_runtime.h>

#define N_NODES 100000
#define NH 64
#define NB 512          // buckets
#define NPB 196         // nodes per bucket (512*196 = 100352 >= N)
#define BCAP 4096       // bucket region capacity (avg 3125, +17 sigma)
#define EPB 8192        // edges per sort block

// ---------------- bf16 helpers (raw bits; RNE rounding) ----------------

__device__ __forceinline__ unsigned short f2bf(float f) {
    union { float f; unsigned int i; } c;
    c.f = f;
    unsigned int b = c.i;
    b += 0x7FFFu + ((b >> 16) & 1u);   // round to nearest even
    return (unsigned short)(b >> 16);
}

__device__ __forceinline__ float bf2f(unsigned short u) {
    union { unsigned int i; float f; } c;
    c.i = ((unsigned int)u) << 16;
    return c.f;
}

// ---------------- CSR build via block-local counting sort ----------------

__global__ __launch_bounds__(256) void k_zero(int* __restrict__ p, int n) {
    int i = blockIdx.x * 256 + threadIdx.x;
    if (i < n) p[i] = 0;
}

// Each block: 8192 edges -> LDS hist over 512 buckets -> scan -> one global
// claim per bucket -> LDS counting sort -> DENSE flush (64B runs, full lines).
__global__ __launch_bounds__(256) void k_sort(const int* __restrict__ src, const int* __restrict__ dst,
                                              int* __restrict__ bcur, unsigned* __restrict__ ebuf, int e) {
    __shared__ unsigned sorted[EPB];        // 32KB
    __shared__ unsigned short cellof[EPB];  // 16KB
    __shared__ int lh[NB];                  // counts
    __shared__ int lbase[NB];               // local exclusive scan
    __shared__ int lcur[NB];                // sort cursors
    __shared__ int gpos[NB];                // claimed base within bucket region
    __shared__ int wsum[4];
    const int t = threadIdx.x;
    const int lane = t & 63, wave = t >> 6;
    const int e0 = blockIdx.x * EPB;
    int cnt = e - e0; if (cnt > EPB) cnt = EPB;

    for (int i = t; i < NB; i += 256) lh[i] = 0;
    __syncthreads();

    // A: histogram bucket ids
    for (int i = t; i < cnt; i += 256) {
        int d = dst[e0 + i];
        atomicAdd(&lh[d / NPB], 1);
    }
    __syncthreads();

    // B: exclusive scan of lh[0..511] (2 entries/thread) + global claims
    const int v0 = lh[2 * t], v1 = lh[2 * t + 1];
    const int s2 = v0 + v1;
    int inc = s2;
#pragma unroll
    for (int d = 1; d < 64; d <<= 1) {
        int u = __shfl_up(inc, d, 64);
        if (lane >= d) inc += u;
    }
    if (lane == 63) wsum[wave] = inc;
    __syncthreads();
    int woff = 0;
#pragma unroll
    for (int w = 0; w < 4; ++w)
        if (w < wave) woff += wsum[w];
    const int excl = woff + inc - s2;
    lbase[2 * t] = excl;
    lbase[2 * t + 1] = excl + v0;
    lcur[2 * t] = excl;
    lcur[2 * t + 1] = excl + v0;
    gpos[2 * t] = atomicAdd(&bcur[2 * t], v0);
    gpos[2 * t + 1] = atomicAdd(&bcur[2 * t + 1], v1);
    __syncthreads();

    // C: counting sort into LDS (re-read edges; L2-hot)
    for (int i = t; i < cnt; i += 256) {
        int d = dst[e0 + i];
        int s = src[e0 + i];
        int b = d / NPB;
        int dl = d - b * NPB;
        int pos = atomicAdd(&lcur[b], 1);
        sorted[pos] = ((unsigned)dl << 17) | (unsigned)s;
        cellof[pos] = (unsigned short)b;
    }
    __syncthreads();

    // D: dense flush — consecutive lanes -> consecutive global addresses
    for (int i = t; i < cnt; i += 256) {
        int c = cellof[i];
        int off = i - lbase[c];
        int gp = gpos[c] + off;
        if (gp < BCAP) ebuf[(long long)c * BCAP + gp] = sorted[i];
    }
}

// single block: exclusive scan of 512 bucket counts -> bstart; rowptr[N] = total
__global__ __launch_bounds__(512) void k_bscan(const int* __restrict__ bcur, int* __restrict__ bstart,
                                               int* __restrict__ rowptr_n) {
    __shared__ int wsum[8];
    const int t = threadIdx.x, lane = t & 63, wave = t >> 6;
    int v = bcur[t];
    if (v > BCAP) v = BCAP;
    int inc = v;
#pragma unroll
    for (int d = 1; d < 64; d <<= 1) {
        int u = __shfl_up(inc, d, 64);
        if (lane >= d) inc += u;
    }
    if (lane == 63) wsum[wave] = inc;
    __syncthreads();
    int woff = 0;
#pragma unroll
    for (int w = 0; w < 8; ++w)
        if (w < wave) woff += wsum[w];
    bstart[t] = woff + inc - v;
    if (t == 511) *rowptr_n = woff + inc;
}

// one block per bucket: stage region in LDS, hist + scan -> rowptr/dinv,
// then L2-hot scatter into the bucket's contiguous csrc slice.
__global__ __launch_bounds__(256) void k_build(const unsigned* __restrict__ ebuf, const int* __restrict__ bcur,
                                               const int* __restrict__ bstart, int* __restrict__ rowptr,
                                               float* __restrict__ dinv, int* __restrict__ csrc, int n) {
    __shared__ unsigned ls[BCAP];
    __shared__ int lh[256];
    __shared__ int lc[256];
    __shared__ int wsum[4];
    const int b = blockIdx.x;
    const int t = threadIdx.x;
    const int node0 = b * NPB;
    int count = bcur[b];
    if (count > BCAP) count = BCAP;
    const int base = bstart[b];

    lh[t] = 0;
    for (int i = t; i < count; i += 256) ls[i] = ebuf[(long long)b * BCAP + i];
    __syncthreads();
    for (int i = t; i < count; i += 256) atomicAdd(&lh[ls[i] >> 17], 1);
    __syncthreads();

    const int lane = t & 63, wave = t >> 6;
    const int v = lh[t];
    int inc = v;
#pragma unroll
    for (int d = 1; d < 64; d <<= 1) {
        int u = __shfl_up(inc, d, 64);
        if (lane >= d) inc += u;
    }
    if (lane == 63) wsum[wave] = inc;
    __syncthreads();
    int woff = 0;
#pragma unroll
    for (int w = 0; w < 4; ++w)
        if (w < wave) woff += wsum[w];
    const int excl = woff + inc - v;

    lc[t] = base + excl;
    const int node = node0 + t;
    if (t < NPB && node < n) {
        rowptr[node] = base + excl;
        dinv[node] = rsqrtf((float)(v + 1));   // +1 self loop
    }
    __syncthreads();

    for (int i = t; i < count; i += 256) {
        unsigned u = ls[i];
        int pos = atomicAdd(&lc[u >> 17], 1);
        csrc[pos] = (int)(u & 0x1FFFFu);
    }
}

// ---------------- GEMM: hs[node][c] = bf16( (sum_k X[node][k]*W[k][c]) * dinv[node] ) ----------

template <int K>
__global__ __launch_bounds__(256) void k_gemm_scale(const float* __restrict__ X, const float* __restrict__ W,
                                                    const float* __restrict__ dinv,
                                                    unsigned short* __restrict__ out, int n) {
    __shared__ float xs[64][132];
    __shared__ float ws[K][64];
    const int tid = threadIdx.x;
    const int n0 = blockIdx.x * 64;

    float* wsf = &ws[0][0];
    for (int idx = tid * 4; idx < K * 64; idx += 1024) {
        *(float4*)&wsf[idx] = *(const float4*)&W[idx];
    }
    const long long base = (long long)n0 * K;
    const long long lim = (long long)n * K;
    for (int idx = tid * 4; idx < 64 * K; idx += 1024) {
        float4 v = make_float4(0.f, 0.f, 0.f, 0.f);
        long long g = base + idx;
        if (g + 3 < lim) v = *(const float4*)&X[g];
        int row = idx / K, col = idx % K;
        *(float4*)&xs[row][col] = v;
    }
    __syncthreads();

    const int tc = tid & 15;
    const int tn = tid >> 4;
    float acc[4][4];
#pragma unroll
    for (int r = 0; r < 4; ++r)
#pragma unroll
        for (int c = 0; c < 4; ++c) acc[r][c] = 0.f;

#pragma unroll 4
    for (int k = 0; k < K; ++k) {
        float4 w = *(const float4*)&ws[k][tc * 4];
        float x0 = xs[4 * tn + 0][k];
        float x1 = xs[4 * tn + 1][k];
        float x2 = xs[4 * tn + 2][k];
        float x3 = xs[4 * tn + 3][k];
        acc[0][0] += x0 * w.x; acc[0][1] += x0 * w.y; acc[0][2] += x0 * w.z; acc[0][3] += x0 * w.w;
        acc[1][0] += x1 * w.x; acc[1][1] += x1 * w.y; acc[1][2] += x1 * w.z; acc[1][3] += x1 * w.w;
        acc[2][0] += x2 * w.x; acc[2][1] += x2 * w.y; acc[2][2] += x2 * w.z; acc[2][3] += x2 * w.w;
        acc[3][0] += x3 * w.x; acc[3][1] += x3 * w.y; acc[3][2] += x3 * w.z; acc[3][3] += x3 * w.w;
    }

#pragma unroll
    for (int r = 0; r < 4; ++r) {
        int node = n0 + 4 * tn + r;
        if (node < n) {
            float dv = dinv[node];
            ushort4 o;
            o.x = f2bf(acc[r][0] * dv);
            o.y = f2bf(acc[r][1] * dv);
            o.z = f2bf(acc[r][2] * dv);
            o.w = f2bf(acc[r][3] * dv);
            *(ushort4*)&out[(long long)node * NH + tc * 4] = o;
        }
    }
}

// ---------------- aggregation: one wave per node, lane = feature ----------------
// 8 independent accumulators -> 8 gathers in flight per wave.

__global__ __launch_bounds__(256) void k_agg(const unsigned short* __restrict__ hs, const float* __restrict__ dinv,
                                             const int* __restrict__ rowptr, const int* __restrict__ csrc,
                                             const float* __restrict__ bias, const float* __restrict__ resid,
                                             float* __restrict__ out, int n) {
    int node = (int)((blockIdx.x * 256 + threadIdx.x) >> 6);
    int lane = threadIdx.x & 63;
    if (node >= n) return;
    node = __builtin_amdgcn_readfirstlane(node);  // wave-uniform -> scalar CSR loads
    long long rowbase = (long long)node * NH;
    float a0 = bf2f(hs[rowbase + lane]);  // self loop
    float a1 = 0.f, a2 = 0.f, a3 = 0.f, a4 = 0.f, a5 = 0.f, a6 = 0.f, a7 = 0.f;
    const int e0 = rowptr[node], e1 = rowptr[node + 1];
    int e = e0;
    for (; e + 8 <= e1; e += 8) {
        int s0 = csrc[e + 0];
        int s1 = csrc[e + 1];
        int s2 = csrc[e + 2];
        int s3 = csrc[e + 3];
        int s4 = csrc[e + 4];
        int s5 = csrc[e + 5];
        int s6 = csrc[e + 6];
        int s7 = csrc[e + 7];
        a0 += bf2f(hs[(long long)s0 * NH + lane]);
        a1 += bf2f(hs[(long long)s1 * NH + lane]);
        a2 += bf2f(hs[(long long)s2 * NH + lane]);
        a3 += bf2f(hs[(long long)s3 * NH + lane]);
        a4 += bf2f(hs[(long long)s4 * NH + lane]);
        a5 += bf2f(hs[(long long)s5 * NH + lane]);
        a6 += bf2f(hs[(long long)s6 * NH + lane]);
        a7 += bf2f(hs[(long long)s7 * NH + lane]);
    }
    for (; e + 4 <= e1; e += 4) {
        int s0 = csrc[e + 0];
        int s1 = csrc[e + 1];
        int s2 = csrc[e + 2];
        int s3 = csrc[e + 3];
        a0 += bf2f(hs[(long long)s0 * NH + lane]);
        a1 += bf2f(hs[(long long)s1 * NH + lane]);
        a2 += bf2f(hs[(long long)s2 * NH + lane]);
        a3 += bf2f(hs[(long long)s3 * NH + lane]);
    }
    for (; e < e1; ++e) {
        int s = csrc[e];
        a0 += bf2f(hs[(long long)s * NH + lane]);
    }
    float acc = ((a0 + a1) + (a2 + a3)) + ((a4 + a5) + (a6 + a7));
    float v = dinv[node] * acc + bias[lane];
    v = fmaxf(v, 0.f);
    if (resid) v += resid[rowbase + lane];
    out[rowbase + lane] = v;
}

// ---------------- launch ----------------

extern "C" void kernel_launch(void* const* d_in, const int* in_sizes, int n_in,
                              void* d_out, int out_size, void* d_ws, size_t ws_size,
                              hipStream_t stream) {
    const float* x  = (const float*)d_in[0];
    const int*   ei = (const int*)d_in[1];
    const float* W1 = (const float*)d_in[2];
    const float* b1 = (const float*)d_in[3];
    const float* W2 = (const float*)d_in[4];
    const float* b2 = (const float*)d_in[5];
    float* out = (float*)d_out;

    const int N = N_NODES;
    const int E = in_sizes[1] / 2;
    const int* src = ei;
    const int* dst = ei + E;

    // workspace layout (element offsets, 16B-aligned). hsb aliases ebuf:
    // ebuf (8.4MB) is dead after k_build; gemm1 overwrites the region (stream-ordered).
    const int NP = 100352;  // padded N (= NB*NPB)
    int*   bcur   = (int*)d_ws;                    // NB
    int*   bstart = bcur + NB;                     // NB
    int*   rowptr = bstart + NB;                   // N+1 (padded to NP)
    float* dinv   = (float*)(rowptr + NP);         // NP
    int*   csrc   = (int*)(dinv + NP);             // E (padded)
    unsigned* ebuf = (unsigned*)(csrc + 1600512);  // NB*BCAP u32 = 8.4MB
    unsigned short* hsb = (unsigned short*)ebuf;   // bf16 [NP][64] = 12.85MB (aliases ebuf)
    float* h1     = (float*)(hsb + (long long)NP * NH);  // fp32 [N][64]

    const int nb_sort = (E + EPB - 1) / EPB;       // 196

    k_zero<<<2, 256, 0, stream>>>(bcur, NB);
    k_sort<<<nb_sort, 256, 0, stream>>>(src, dst, bcur, ebuf, E);
    k_bscan<<<1, 512, 0, stream>>>(bcur, bstart, rowptr + N);
    k_build<<<NB, 256, 0, stream>>>(ebuf, bcur, bstart, rowptr, dinv, csrc, N);

    // layer 1
    k_gemm_scale<128><<<(N + 63) / 64, 256, 0, stream>>>(x, W1, dinv, hsb, N);
    k_agg<<<(N + 3) / 4, 256, 0, stream>>>(hsb, dinv, rowptr, csrc, b1, nullptr, h1, N);

    // layer 2 (+ residual h1)
    k_gemm_scale<64><<<(N + 63) / 64, 256, 0, stream>>>(h1, W2, dinv, hsb, N);
    k_agg<<<(N + 3) / 4, 256, 0, stream>>>(hsb, dinv, rowptr, csrc, b2, h1, out, N);
}

// Round 8
// 194.881 us; speedup vs baseline: 4.1612x; 1.0255x over previous
//
#include <hip/hip_runtime.h>

#define N_NODES 100000
#define NH 64
#define NB 512          // buckets
#define NPB 196         // nodes per bucket (512*196 = 100352 >= N)
#define BCAP 4096       // raw bucket capacity (avg 3125, +17 sigma)
#define PBCAP 7040      // padded bucket region (4096 + 196*15 rounded to 16)
#define EPB 8192        // edges per sort block

// ---------------- bf16 helpers (raw bits; RNE rounding) ----------------

__device__ __forceinline__ unsigned short f2bf(float f) {
    union { float f; unsigned int i; } c;
    c.f = f;
    unsigned int b = c.i;
    b += 0x7FFFu + ((b >> 16) & 1u);   // round to nearest even
    return (unsigned short)(b >> 16);
}

__device__ __forceinline__ float bf2f(unsigned short u) {
    union { unsigned int i; float f; } c;
    c.i = ((unsigned int)u) << 16;
    return c.f;
}

// ---------------- CSR build via block-local counting sort ----------------

__global__ __launch_bounds__(256) void k_zero(int* __restrict__ p, int n) {
    int i = blockIdx.x * 256 + threadIdx.x;
    if (i < n) p[i] = 0;
}

// Each block: 8192 edges -> LDS hist over 512 buckets -> scan -> one global
// claim per bucket -> LDS counting sort -> DENSE flush (full 64B lines).
__global__ __launch_bounds__(256) void k_sort(const int* __restrict__ src, const int* __restrict__ dst,
                                              int* __restrict__ bcur, unsigned* __restrict__ ebuf, int e) {
    __shared__ unsigned sorted[EPB];        // 32KB
    __shared__ unsigned short cellof[EPB];  // 16KB
    __shared__ int lh[NB];
    __shared__ int lbase[NB];
    __shared__ int lcur[NB];
    __shared__ int gpos[NB];
    __shared__ int wsum[4];
    const int t = threadIdx.x;
    const int lane = t & 63, wave = t >> 6;
    const int e0 = blockIdx.x * EPB;
    int cnt = e - e0; if (cnt > EPB) cnt = EPB;

    for (int i = t; i < NB; i += 256) lh[i] = 0;
    __syncthreads();

    // A: histogram bucket ids
    for (int i = t; i < cnt; i += 256) {
        int d = dst[e0 + i];
        atomicAdd(&lh[d / NPB], 1);
    }
    __syncthreads();

    // B: exclusive scan (2 entries/thread) + global claims
    const int v0 = lh[2 * t], v1 = lh[2 * t + 1];
    const int s2 = v0 + v1;
    int inc = s2;
#pragma unroll
    for (int d = 1; d < 64; d <<= 1) {
        int u = __shfl_up(inc, d, 64);
        if (lane >= d) inc += u;
    }
    if (lane == 63) wsum[wave] = inc;
    __syncthreads();
    int woff = 0;
#pragma unroll
    for (int w = 0; w < 4; ++w)
        if (w < wave) woff += wsum[w];
    const int excl = woff + inc - s2;
    lbase[2 * t] = excl;
    lbase[2 * t + 1] = excl + v0;
    lcur[2 * t] = excl;
    lcur[2 * t + 1] = excl + v0;
    gpos[2 * t] = atomicAdd(&bcur[2 * t], v0);
    gpos[2 * t + 1] = atomicAdd(&bcur[2 * t + 1], v1);
    __syncthreads();

    // C: counting sort into LDS (re-read edges; L2-hot)
    for (int i = t; i < cnt; i += 256) {
        int d = dst[e0 + i];
        int s = src[e0 + i];
        int b = d / NPB;
        int dl = d - b * NPB;
        int pos = atomicAdd(&lcur[b], 1);
        sorted[pos] = ((unsigned)dl << 17) | (unsigned)s;
        cellof[pos] = (unsigned short)b;
    }
    __syncthreads();

    // D: dense flush — consecutive lanes -> consecutive global addresses
    for (int i = t; i < cnt; i += 256) {
        int c = cellof[i];
        int off = i - lbase[c];
        int gp = gpos[c] + off;
        if (gp < BCAP) ebuf[(long long)c * BCAP + gp] = sorted[i];
    }
}

// one block per bucket: stage region in LDS, hist + PADDED scan -> rowptr/degp/dinv,
// scatter into the bucket's fixed csrc region [b*PBCAP ...), pad rows to mult of 16
// with -1 sentinels.
__global__ __launch_bounds__(256) void k_build(const unsigned* __restrict__ ebuf, const int* __restrict__ bcur,
                                               int* __restrict__ rowptr, int* __restrict__ degp,
                                               float* __restrict__ dinv, int* __restrict__ csrc, int n) {
    __shared__ unsigned ls[BCAP];
    __shared__ int lh[256];
    __shared__ int lstart[256];
    __shared__ int lc[256];
    __shared__ int wsum[4];
    const int b = blockIdx.x;
    const int t = threadIdx.x;
    const int node0 = b * NPB;
    int count = bcur[b];
    if (count > BCAP) count = BCAP;
    const int rbase = b * PBCAP;

    lh[t] = 0;
    for (int i = t; i < count; i += 256) ls[i] = ebuf[(long long)b * BCAP + i];
    __syncthreads();
    for (int i = t; i < count; i += 256) atomicAdd(&lh[ls[i] >> 17], 1);
    __syncthreads();

    const int lane = t & 63, wave = t >> 6;
    const int v = lh[t];
    const int pv = (v + 15) & ~15;          // padded degree
    int inc = pv;
#pragma unroll
    for (int d = 1; d < 64; d <<= 1) {
        int u = __shfl_up(inc, d, 64);
        if (lane >= d) inc += u;
    }
    if (lane == 63) wsum[wave] = inc;
    __syncthreads();
    int woff = 0;
#pragma unroll
    for (int w = 0; w < 4; ++w)
        if (w < wave) woff += wsum[w];
    const int start = rbase + woff + inc - pv;

    lstart[t] = start;
    lc[t] = start;
    const int node = node0 + t;
    if (t < NPB && node < n) {
        rowptr[node] = start;
        degp[node] = pv;
        dinv[node] = rsqrtf((float)(v + 1));   // +1 self loop
    }
    __syncthreads();

    for (int i = t; i < count; i += 256) {
        unsigned u = ls[i];
        int pos = atomicAdd(&lc[u >> 17], 1);
        csrc[pos] = (int)(u & 0x1FFFFu);
    }
    __syncthreads();

    // pad tail of own node's row with sentinels
    const int pend = lstart[t] + pv;
    for (int p = lc[t]; p < pend; ++p) csrc[p] = -1;
}

// ---------------- GEMM: hs[node][c] = bf16( (sum_k X[node][k]*W[k][c]) * dinv[node] ) ----------
// K-split (64-wide panels): LDS = 33.8KB -> 4 blocks/CU.

template <int K>
__global__ __launch_bounds__(256) void k_gemm_scale(const float* __restrict__ X, const float* __restrict__ W,
                                                    const float* __restrict__ dinv,
                                                    unsigned short* __restrict__ out, int n) {
    __shared__ float xs[64][68];   // 17.4KB (+4 pad)
    __shared__ float ws[64][64];   // 16.4KB
    const int tid = threadIdx.x;
    const int n0 = blockIdx.x * 64;
    const int tc = tid & 15;
    const int tn = tid >> 4;

    float acc[4][4];
#pragma unroll
    for (int r = 0; r < 4; ++r)
#pragma unroll
        for (int c = 0; c < 4; ++c) acc[r][c] = 0.f;

    for (int kb = 0; kb < K; kb += 64) {
        for (int idx = tid * 4; idx < 64 * 64; idx += 1024) {
            int row = idx >> 6, col = idx & 63;
            *(float4*)&ws[row][col] = *(const float4*)&W[(kb + row) * NH + col];
        }
        for (int idx = tid * 4; idx < 64 * 64; idx += 1024) {
            int row = idx >> 6, col = idx & 63;
            float4 v = make_float4(0.f, 0.f, 0.f, 0.f);
            if (n0 + row < n) v = *(const float4*)&X[(long long)(n0 + row) * K + kb + col];
            *(float4*)&xs[row][col] = v;
        }
        __syncthreads();

#pragma unroll 4
        for (int k = 0; k < 64; ++k) {
            float4 w = *(const float4*)&ws[k][tc * 4];
            float x0 = xs[4 * tn + 0][k];
            float x1 = xs[4 * tn + 1][k];
            float x2 = xs[4 * tn + 2][k];
            float x3 = xs[4 * tn + 3][k];
            acc[0][0] += x0 * w.x; acc[0][1] += x0 * w.y; acc[0][2] += x0 * w.z; acc[0][3] += x0 * w.w;
            acc[1][0] += x1 * w.x; acc[1][1] += x1 * w.y; acc[1][2] += x1 * w.z; acc[1][3] += x1 * w.w;
            acc[2][0] += x2 * w.x; acc[2][1] += x2 * w.y; acc[2][2] += x2 * w.z; acc[2][3] += x2 * w.w;
            acc[3][0] += x3 * w.x; acc[3][1] += x3 * w.y; acc[3][2] += x3 * w.z; acc[3][3] += x3 * w.w;
        }
        __syncthreads();
    }

#pragma unroll
    for (int r = 0; r < 4; ++r) {
        int node = n0 + 4 * tn + r;
        if (node < n) {
            float dv = dinv[node];
            ushort4 o;
            o.x = f2bf(acc[r][0] * dv);
            o.y = f2bf(acc[r][1] * dv);
            o.z = f2bf(acc[r][2] * dv);
            o.w = f2bf(acc[r][3] * dv);
            *(ushort4*)&out[(long long)node * NH + tc * 4] = o;
        }
    }
}

// ---------------- aggregation: one wave per node, lane = feature ----------------
// padded CSR (deg multiple of 16): every iteration issues 16 gathers.
// sentinel (-1) redirects to own row (L1-hot) and contributes exact 0.

__global__ __launch_bounds__(256) void k_agg(const unsigned short* __restrict__ hs, const float* __restrict__ dinv,
                                             const int* __restrict__ rowptr, const int* __restrict__ degp,
                                             const int* __restrict__ csrc,
                                             const float* __restrict__ bias, const float* __restrict__ resid,
                                             float* __restrict__ out, int n) {
    int node = (int)((blockIdx.x * 256 + threadIdx.x) >> 6);
    int lane = threadIdx.x & 63;
    if (node >= n) return;
    node = __builtin_amdgcn_readfirstlane(node);  // wave-uniform -> scalar CSR loads
    long long rowbase = (long long)node * NH;
    float a[16];
    a[0] = bf2f(hs[rowbase + lane]);  // self loop
#pragma unroll
    for (int j = 1; j < 16; ++j) a[j] = 0.f;
    const int e0 = rowptr[node];
    const int e1 = e0 + degp[node];
    for (int e = e0; e < e1; e += 16) {
        int4 c0 = *(const int4*)&csrc[e + 0];
        int4 c1 = *(const int4*)&csrc[e + 4];
        int4 c2 = *(const int4*)&csrc[e + 8];
        int4 c3 = *(const int4*)&csrc[e + 12];
        int s[16] = {c0.x, c0.y, c0.z, c0.w, c1.x, c1.y, c1.z, c1.w,
                     c2.x, c2.y, c2.z, c2.w, c3.x, c3.y, c3.z, c3.w};
#pragma unroll
        for (int j = 0; j < 16; ++j) {
            int sr = s[j];
            long long si = (sr < 0) ? (long long)node : (long long)sr;
            float v = bf2f(hs[si * NH + lane]);
            a[j] += (sr < 0) ? 0.f : v;
        }
    }
    float acc = (((a[0] + a[1]) + (a[2] + a[3])) + ((a[4] + a[5]) + (a[6] + a[7]))) +
                (((a[8] + a[9]) + (a[10] + a[11])) + ((a[12] + a[13]) + (a[14] + a[15])));
    float v = dinv[node] * acc + bias[lane];
    v = fmaxf(v, 0.f);
    if (resid) v += resid[rowbase + lane];
    out[rowbase + lane] = v;
}

// ---------------- launch ----------------

extern "C" void kernel_launch(void* const* d_in, const int* in_sizes, int n_in,
                              void* d_out, int out_size, void* d_ws, size_t ws_size,
                              hipStream_t stream) {
    const float* x  = (const float*)d_in[0];
    const int*   ei = (const int*)d_in[1];
    const float* W1 = (const float*)d_in[2];
    const float* b1 = (const float*)d_in[3];
    const float* W2 = (const float*)d_in[4];
    const float* b2 = (const float*)d_in[5];
    float* out = (float*)d_out;

    const int N = N_NODES;
    const int E = in_sizes[1] / 2;
    const int* src = ei;
    const int* dst = ei + E;

    // workspace layout (element offsets, 16B-aligned). hsb aliases ebuf:
    // ebuf (8.4MB) is dead after k_build; gemm1 overwrites the region (stream-ordered).
    const int NP = 100352;  // padded N (= NB*NPB)
    int*   bcur   = (int*)d_ws;                    // NB
    int*   rowptr = bcur + NB;                     // NP
    int*   degp   = rowptr + NP;                   // NP
    float* dinv   = (float*)(degp + NP);           // NP
    int*   csrc   = (int*)(dinv + NP);             // NB*PBCAP = 3.6M ints (14.4MB)
    unsigned* ebuf = (unsigned*)(csrc + NB * PBCAP); // NB*BCAP u32 = 8.4MB
    unsigned short* hsb = (unsigned short*)ebuf;   // bf16 [NP][64] = 12.85MB (aliases ebuf)
    float* h1     = (float*)(hsb + (long long)NP * NH);  // fp32 [N][64] = 25.6MB

    const int nb_sort = (E + EPB - 1) / EPB;       // 196

    k_zero<<<2, 256, 0, stream>>>(bcur, NB);
    k_sort<<<nb_sort, 256, 0, stream>>>(src, dst, bcur, ebuf, E);
    k_build<<<NB, 256, 0, stream>>>(ebuf, bcur, rowptr, degp, dinv, csrc, N);

    // layer 1
    k_gemm_scale<128><<<(N + 63) / 64, 256, 0, stream>>>(x, W1, dinv, hsb, N);
    k_agg<<<(N + 3) / 4, 256, 0, stream>>>(hsb, dinv, rowptr, degp, csrc, b1, nullptr, h1, N);

    // layer 2 (+ residual h1)
    k_gemm_scale<64><<<(N + 63) / 64, 256, 0, stream>>>(h1, W2, dinv, hsb, N);
    k_agg<<<(N + 3) / 4, 256, 0, stream>>>(hsb, dinv, rowptr, degp, csrc, b2, h1, out, N);
}

// Round 10
// 172.465 us; speedup vs baseline: 4.7021x; 1.1300x over previous
//
#include <hip/hip_runtime.h>

#define N_NODES 100000
#define NDUMMY 100000   // dummy zero row index (padded table row)
#define NH 64
#define NB 512          // buckets
#define NPB 196         // nodes per bucket (512*196 = 100352 >= N)
#define BCAP 4096       // raw bucket capacity (avg 3125, +17 sigma)
#define PBCAP 5472      // padded bucket region (4096 + 196*7, rounded to 16)
#define EPB 8192        // edges per sort block

// ---------------- bf16 helpers ----------------

__device__ __forceinline__ unsigned short f2bf(float f) {
    union { float f; unsigned int i; } c;
    c.f = f;
    unsigned int b = c.i;
    b += 0x7FFFu + ((b >> 16) & 1u);   // round to nearest even
    return (unsigned short)(b >> 16);
}

__device__ __forceinline__ float bfLO(unsigned u) {   // low bf16 of packed pair
    union { unsigned i; float f; } c; c.i = u << 16; return c.f;
}
__device__ __forceinline__ float bfHI(unsigned u) {   // high bf16 of packed pair
    union { unsigned i; float f; } c; c.i = u & 0xFFFF0000u; return c.f;
}

// ---------------- init: zero bucket cursors + dummy hs row ----------------

__global__ __launch_bounds__(512) void k_init(int* __restrict__ bcur, unsigned* __restrict__ dummy_row) {
    int t = threadIdx.x;
    if (t < NB) bcur[t] = 0;
    if (t < 32) dummy_row[t] = 0;   // 128B bf16 row of zeros
}

// ---------------- CSR build via block-local counting sort ----------------

__global__ __launch_bounds__(256) void k_sort(const int* __restrict__ src, const int* __restrict__ dst,
                                              int* __restrict__ bcur, unsigned* __restrict__ ebuf, int e) {
    __shared__ unsigned sorted[EPB];        // 32KB
    __shared__ unsigned short cellof[EPB];  // 16KB
    __shared__ int lh[NB];
    __shared__ int lbase[NB];
    __shared__ int lcur[NB];
    __shared__ int gpos[NB];
    __shared__ int wsum[4];
    const int t = threadIdx.x;
    const int lane = t & 63, wave = t >> 6;
    const int e0 = blockIdx.x * EPB;
    int cnt = e - e0; if (cnt > EPB) cnt = EPB;

    for (int i = t; i < NB; i += 256) lh[i] = 0;
    __syncthreads();

    for (int i = t; i < cnt; i += 256) {
        int d = dst[e0 + i];
        atomicAdd(&lh[d / NPB], 1);
    }
    __syncthreads();

    const int v0 = lh[2 * t], v1 = lh[2 * t + 1];
    const int s2 = v0 + v1;
    int inc = s2;
#pragma unroll
    for (int d = 1; d < 64; d <<= 1) {
        int u = __shfl_up(inc, d, 64);
        if (lane >= d) inc += u;
    }
    if (lane == 63) wsum[wave] = inc;
    __syncthreads();
    int woff = 0;
#pragma unroll
    for (int w = 0; w < 4; ++w)
        if (w < wave) woff += wsum[w];
    const int excl = woff + inc - s2;
    lbase[2 * t] = excl;
    lbase[2 * t + 1] = excl + v0;
    lcur[2 * t] = excl;
    lcur[2 * t + 1] = excl + v0;
    gpos[2 * t] = atomicAdd(&bcur[2 * t], v0);
    gpos[2 * t + 1] = atomicAdd(&bcur[2 * t + 1], v1);
    __syncthreads();

    for (int i = t; i < cnt; i += 256) {
        int d = dst[e0 + i];
        int s = src[e0 + i];
        int b = d / NPB;
        int dl = d - b * NPB;
        int pos = atomicAdd(&lcur[b], 1);
        sorted[pos] = ((unsigned)dl << 17) | (unsigned)s;
        cellof[pos] = (unsigned short)b;
    }
    __syncthreads();

    for (int i = t; i < cnt; i += 256) {
        int c = cellof[i];
        int off = i - lbase[c];
        int gp = gpos[c] + off;
        if (gp < BCAP) ebuf[(long long)c * BCAP + gp] = sorted[i];
    }
}

// one block per bucket: stage region in LDS, hist + PADDED scan -> rowptr/degp/dinv,
// scatter into fixed csrc region [b*PBCAP ...), pad rows to mult of 8 with NDUMMY.
__global__ __launch_bounds__(256) void k_build(const unsigned* __restrict__ ebuf, const int* __restrict__ bcur,
                                               int* __restrict__ rowptr, int* __restrict__ degp,
                                               float* __restrict__ dinv, int* __restrict__ csrc, int n) {
    __shared__ unsigned ls[BCAP];
    __shared__ int lh[256];
    __shared__ int lstart[256];
    __shared__ int lc[256];
    __shared__ int wsum[4];
    const int b = blockIdx.x;
    const int t = threadIdx.x;
    const int node0 = b * NPB;
    int count = bcur[b];
    if (count > BCAP) count = BCAP;
    const int rbase = b * PBCAP;

    lh[t] = 0;
    for (int i = t; i < count; i += 256) ls[i] = ebuf[(long long)b * BCAP + i];
    __syncthreads();
    for (int i = t; i < count; i += 256) atomicAdd(&lh[ls[i] >> 17], 1);
    __syncthreads();

    const int lane = t & 63, wave = t >> 6;
    const int v = lh[t];
    const int pv = (v + 7) & ~7;            // padded degree (mult of 8)
    int inc = pv;
#pragma unroll
    for (int d = 1; d < 64; d <<= 1) {
        int u = __shfl_up(inc, d, 64);
        if (lane >= d) inc += u;
    }
    if (lane == 63) wsum[wave] = inc;
    __syncthreads();
    int woff = 0;
#pragma unroll
    for (int w = 0; w < 4; ++w)
        if (w < wave) woff += wsum[w];
    const int start = rbase + woff + inc - pv;

    lstart[t] = start;
    lc[t] = start;
    const int node = node0 + t;
    if (t < NPB && node < n) {
        rowptr[node] = start;
        degp[node] = pv;
        dinv[node] = rsqrtf((float)(v + 1));   // +1 self loop
    }
    __syncthreads();

    for (int i = t; i < count; i += 256) {
        unsigned u = ls[i];
        int pos = atomicAdd(&lc[u >> 17], 1);
        csrc[pos] = (int)(u & 0x1FFFFu);
    }
    __syncthreads();

    const int pend = lstart[t] + pv;
    for (int p = lc[t]; p < pend; ++p) csrc[p] = NDUMMY;
}

// ---------------- GEMM: hs[node][c] = bf16( (sum_k X[node][k]*W[k][c]) * dinv[node] ) ----------
// K-split (64-wide panels): LDS = 33.8KB -> 4 blocks/CU.

template <int K>
__global__ __launch_bounds__(256) void k_gemm_scale(const float* __restrict__ X, const float* __restrict__ W,
                                                    const float* __restrict__ dinv,
                                                    unsigned short* __restrict__ out, int n) {
    __shared__ float xs[64][68];   // +4 pad
    __shared__ float ws[64][64];
    const int tid = threadIdx.x;
    const int n0 = blockIdx.x * 64;
    const int tc = tid & 15;
    const int tn = tid >> 4;

    float acc[4][4];
#pragma unroll
    for (int r = 0; r < 4; ++r)
#pragma unroll
        for (int c = 0; c < 4; ++c) acc[r][c] = 0.f;

    for (int kb = 0; kb < K; kb += 64) {
        for (int idx = tid * 4; idx < 64 * 64; idx += 1024) {
            int row = idx >> 6, col = idx & 63;
            *(float4*)&ws[row][col] = *(const float4*)&W[(kb + row) * NH + col];
        }
        for (int idx = tid * 4; idx < 64 * 64; idx += 1024) {
            int row = idx >> 6, col = idx & 63;
            float4 v = make_float4(0.f, 0.f, 0.f, 0.f);
            if (n0 + row < n) v = *(const float4*)&X[(long long)(n0 + row) * K + kb + col];
            *(float4*)&xs[row][col] = v;
        }
        __syncthreads();

#pragma unroll 4
        for (int k = 0; k < 64; ++k) {
            float4 w = *(const float4*)&ws[k][tc * 4];
            float x0 = xs[4 * tn + 0][k];
            float x1 = xs[4 * tn + 1][k];
            float x2 = xs[4 * tn + 2][k];
            float x3 = xs[4 * tn + 3][k];
            acc[0][0] += x0 * w.x; acc[0][1] += x0 * w.y; acc[0][2] += x0 * w.z; acc[0][3] += x0 * w.w;
            acc[1][0] += x1 * w.x; acc[1][1] += x1 * w.y; acc[1][2] += x1 * w.z; acc[1][3] += x1 * w.w;
            acc[2][0] += x2 * w.x; acc[2][1] += x2 * w.y; acc[2][2] += x2 * w.z; acc[2][3] += x2 * w.w;
            acc[3][0] += x3 * w.x; acc[3][1] += x3 * w.y; acc[3][2] += x3 * w.z; acc[3][3] += x3 * w.w;
        }
        __syncthreads();
    }

#pragma unroll
    for (int r = 0; r < 4; ++r) {
        int node = n0 + 4 * tn + r;
        if (node < n) {
            float dv = dinv[node];
            ushort4 o;
            o.x = f2bf(acc[r][0] * dv);
            o.y = f2bf(acc[r][1] * dv);
            o.z = f2bf(acc[r][2] * dv);
            o.w = f2bf(acc[r][3] * dv);
            *(ushort4*)&out[(long long)node * NH + tc * 4] = o;
        }
    }
}

// ---------------- aggregation: 2 nodes/wave, lane loads packed uint (2 bf16) ----------------
// Each 256-thread block covers 4 waves x 2 = 8 nodes.

__global__ __launch_bounds__(256) void k_agg(const unsigned* __restrict__ hs32, const float* __restrict__ dinv,
                                             const int* __restrict__ rowptr, const int* __restrict__ degp,
                                             const int* __restrict__ csrc,
                                             const float* __restrict__ bias, const float* __restrict__ resid,
                                             float* __restrict__ out, int n) {
    const int gt = blockIdx.x * 256 + threadIdx.x;
    const int wave = gt >> 6;
    const int lane = threadIdx.x & 63;
    const int half = lane >> 5;
    const int li = lane & 31;               // uint index within row (features 2li, 2li+1)
    const int node = wave * 2 + half;
    if (node >= n) return;

    const int rowb = node * 32;
    unsigned su = hs32[rowb + li];          // self loop
    float aL0 = bfLO(su), aH0 = bfHI(su);
    float aL1 = 0.f, aH1 = 0.f, aL2 = 0.f, aH2 = 0.f, aL3 = 0.f, aH3 = 0.f;
    float aL4 = 0.f, aH4 = 0.f, aL5 = 0.f, aH5 = 0.f, aL6 = 0.f, aH6 = 0.f, aL7 = 0.f, aH7 = 0.f;

    const int e0 = rowptr[node];
    const int e1 = e0 + degp[node];
    for (int e = e0; e < e1; e += 8) {
        int4 c0 = *(const int4*)&csrc[e];
        int4 c1 = *(const int4*)&csrc[e + 4];
        unsigned u0 = hs32[c0.x * 32 + li];
        unsigned u1 = hs32[c0.y * 32 + li];
        unsigned u2 = hs32[c0.z * 32 + li];
        unsigned u3 = hs32[c0.w * 32 + li];
        unsigned u4 = hs32[c1.x * 32 + li];
        unsigned u5 = hs32[c1.y * 32 + li];
        unsigned u6 = hs32[c1.z * 32 + li];
        unsigned u7 = hs32[c1.w * 32 + li];
        aL0 += bfLO(u0); aH0 += bfHI(u0);
        aL1 += bfLO(u1); aH1 += bfHI(u1);
        aL2 += bfLO(u2); aH2 += bfHI(u2);
        aL3 += bfLO(u3); aH3 += bfHI(u3);
        aL4 += bfLO(u4); aH4 += bfHI(u4);
        aL5 += bfLO(u5); aH5 += bfHI(u5);
        aL6 += bfLO(u6); aH6 += bfHI(u6);
        aL7 += bfLO(u7); aH7 += bfHI(u7);
    }
    float accL = ((aL0 + aL1) + (aL2 + aL3)) + ((aL4 + aL5) + (aL6 + aL7));
    float accH = ((aH0 + aH1) + (aH2 + aH3)) + ((aH4 + aH5) + (aH6 + aH7));

    const float dv = dinv[node];
    const float2 bb = *(const float2*)&bias[2 * li];
    float vL = fmaxf(dv * accL + bb.x, 0.f);
    float vH = fmaxf(dv * accH + bb.y, 0.f);
    const long long ob = (long long)node * NH + 2 * li;
    if (resid) {
        float2 rr = *(const float2*)&resid[ob];
        vL += rr.x; vH += rr.y;
    }
    *(float2*)&out[ob] = make_float2(vL, vH);
}

// ---------------- launch ----------------

extern "C" void kernel_launch(void* const* d_in, const int* in_sizes, int n_in,
                              void* d_out, int out_size, void* d_ws, size_t ws_size,
                              hipStream_t stream) {
    const float* x  = (const float*)d_in[0];
    const int*   ei = (const int*)d_in[1];
    const float* W1 = (const float*)d_in[2];
    const float* b1 = (const float*)d_in[3];
    const float* W2 = (const float*)d_in[4];
    const float* b2 = (const float*)d_in[5];
    float* out = (float*)d_out;

    const int N = N_NODES;
    const int E = in_sizes[1] / 2;
    const int* src = ei;
    const int* dst = ei + E;

    // workspace layout (element offsets, 16B-aligned). hsb aliases ebuf:
    // ebuf (8.4MB) is dead after k_build; gemm1 overwrites the region (stream-ordered).
    // Dummy row NDUMMY (offset 12.80MB) is beyond ebuf (8.39MB) -> survives k_sort.
    const int NP = 100352;  // padded N (= NB*NPB)
    int*   bcur   = (int*)d_ws;                      // NB
    int*   rowptr = bcur + NB;                       // NP
    int*   degp   = rowptr + NP;                     // NP
    float* dinv   = (float*)(degp + NP);             // NP
    int*   csrc   = (int*)(dinv + NP);               // NB*PBCAP = 2.80M ints
    unsigned* ebuf = (unsigned*)(csrc + NB * PBCAP); // NB*BCAP u32 = 8.39MB
    unsigned* hs32 = ebuf;                           // packed bf16 [NP+..][32] (aliases ebuf)
    unsigned short* hsb = (unsigned short*)hs32;
    float* h1     = (float*)(hs32 + (long long)(NDUMMY + 1) * 32);  // fp32 [N][64]

    const int nb_sort = (E + EPB - 1) / EPB;         // 196

    k_init<<<1, 512, 0, stream>>>(bcur, hs32 + (long long)NDUMMY * 32);
    k_sort<<<nb_sort, 256, 0, stream>>>(src, dst, bcur, ebuf, E);
    k_build<<<NB, 256, 0, stream>>>(ebuf, bcur, rowptr, degp, dinv, csrc, N);

    // layer 1
    k_gemm_scale<128><<<(N + 63) / 64, 256, 0, stream>>>(x, W1, dinv, hsb, N);
    k_agg<<<(N + 7) / 8, 256, 0, stream>>>(hs32, dinv, rowptr, degp, csrc, b1, nullptr, h1, N);

    // layer 2 (+ residual h1)
    k_gemm_scale<64><<<(N + 63) / 64, 256, 0, stream>>>(h1, W2, dinv, hsb, N);
    k_agg<<<(N + 7) / 8, 256, 0, stream>>>(hs32, dinv, rowptr, degp, csrc, b2, h1, out, N);
}